// Round 15
// baseline (205.587 us; speedup 1.0000x reference)
//
#include <hip/hip_runtime.h>
#include <math.h>

#define N_NODES 50000
#define N_EDGES 800000
#define NFEAT 128
#define NHID 64
#define NCLASS 40
#define LN_EPS 1e-5f
#define BROWS 64                                // rows per bucket
#define NBUCK ((N_NODES + BROWS - 1) / BROWS)   // 782
#define CHUNK 4096                              // edges per hist chunk
#define NCHUNK ((N_EDGES + CHUNK - 1) / CHUNK)  // 196
#define SCHUNK 2048                             // edges per scatter chunk
#define SNCHUNK ((N_EDGES + SCHUNK - 1) / SCHUNK) // 391
#define NPB 16                                  // nodes per agg block
#define H2STRIDE 48                             // ushorts/row (96B)

__device__ __forceinline__ int swz(int k) { return ((k >> 2) & 7) << 2; }

__device__ __forceinline__ unsigned packbf(float a, float b) {
  unsigned ua = __float_as_uint(a), ub = __float_as_uint(b);
  ua += 0x7fffu + ((ua >> 16) & 1u);
  ub += 0x7fffu + ((ub >> 16) & 1u);
  return (ua >> 16) | (ub & 0xffff0000u);
}
__device__ __forceinline__ unsigned bf16hi(float a) {
  unsigned u = __float_as_uint(a);
  u += 0x7fffu + ((u >> 16) & 1u);
  return u & 0xffff0000u;
}
__device__ __forceinline__ float lo16(unsigned v) { return __uint_as_float(v << 16); }
__device__ __forceinline__ float hi16(unsigned v) { return __uint_as_float(v & 0xffff0000u); }

// ------ Kernel A: h1 = x @ W1 (reg-blocked 4x4) + fused s_src/s_dst ------------
// block 0 also zeroes bcnt (stream order: completes before k_resmm's histogram)
__global__ __launch_bounds__(256) void k_h1mm(const float* __restrict__ x,
    const float* __restrict__ W1, const float* __restrict__ a1,
    unsigned* __restrict__ h1u, float* __restrict__ s_src, float* __restrict__ s_dst,
    int* __restrict__ bcnt) {
  __shared__ float xT[NFEAT * 64];    // 32 KB
  __shared__ float W1s[NFEAT * NHID]; // 32 KB
  int t = threadIdx.x;
  if (blockIdx.x == 0)
    for (int i = t; i < NBUCK; i += 256) bcnt[i] = 0;
  int R0 = blockIdx.x * 64;
  for (int i = t; i < NFEAT * NHID / 4; i += 256)
    ((float4*)W1s)[i] = ((const float4*)W1)[i];
#pragma unroll
  for (int it = 0; it < 8; ++it) {
    int i = t + it * 256;
    int r = i >> 5, kq = i & 31;
    int gr = R0 + r;
    float4 v = make_float4(0.f, 0.f, 0.f, 0.f);
    if (gr < N_NODES) v = *(const float4*)(x + (size_t)gr * NFEAT + kq * 4);
    int rw = r ^ ((kq & 7) << 2);
    xT[(kq * 4 + 0) * 64 + rw] = v.x;
    xT[(kq * 4 + 1) * 64 + rw] = v.y;
    xT[(kq * 4 + 2) * 64 + rw] = v.z;
    xT[(kq * 4 + 3) * 64 + rw] = v.w;
  }
  __syncthreads();
  int cg = t & 15, rg = t >> 4;
  int c0 = cg * 4, r0 = rg * 4;
  float acc[4][4] = {};
#pragma unroll 4
  for (int k = 0; k < NFEAT; ++k) {
    float4 xv = *(const float4*)&xT[k * 64 + (r0 ^ swz(k))];
    float4 wv = *(const float4*)&W1s[k * NHID + c0];
    float xr[4] = {xv.x, xv.y, xv.z, xv.w};
    float wr[4] = {wv.x, wv.y, wv.z, wv.w};
#pragma unroll
    for (int j = 0; j < 4; ++j)
#pragma unroll
      for (int c = 0; c < 4; ++c)
        acc[j][c] = fmaf(xr[j], wr[c], acc[j][c]);
  }
  float4 as = *(const float4*)(a1 + c0);
  float4 ad = *(const float4*)(a1 + NHID + c0);
  float asr[4] = {as.x, as.y, as.z, as.w};
  float adr[4] = {ad.x, ad.y, ad.z, ad.w};
  float ps[4], pd[4];
#pragma unroll
  for (int j = 0; j < 4; ++j) {
    int gr = R0 + r0 + j;
    if (gr < N_NODES) {
      uint2 pk;
      pk.x = packbf(acc[j][0], acc[j][1]);
      pk.y = packbf(acc[j][2], acc[j][3]);
      *(uint2*)&h1u[(size_t)gr * 32 + (c0 >> 1)] = pk;
    }
    float s = 0.f, d = 0.f;
#pragma unroll
    for (int c = 0; c < 4; ++c) {
      s = fmaf(acc[j][c], asr[c], s);
      d = fmaf(acc[j][c], adr[c], d);
    }
    ps[j] = s; pd[j] = d;
  }
#pragma unroll
  for (int j = 0; j < 4; ++j)
#pragma unroll
    for (int off = 1; off < 16; off <<= 1) {
      ps[j] += __shfl_xor(ps[j], off);
      pd[j] += __shfl_xor(pd[j], off);
    }
  if (cg == 0) {
#pragma unroll
    for (int j = 0; j < 4; ++j) {
      int gr = R0 + r0 + j;
      if (gr < N_NODES) { s_src[gr] = ps[j]; s_dst[gr] = pd[j]; }
    }
  }
}

// ------ Kernel R: res = x @ res_w^T + res_b (4x5) + fused bucket histogram -----
__global__ __launch_bounds__(256) void k_resmm(const float* __restrict__ x,
    const float* __restrict__ res_w, const float* __restrict__ res_b,
    float* __restrict__ res, const int* __restrict__ ei, int* __restrict__ bcnt) {
  __shared__ float xT[NFEAT * 128];     // 64 KB
  __shared__ float rwT[NFEAT * NCLASS]; // 20 KB
  int t = threadIdx.x;
  int R0 = blockIdx.x * 128;
  for (int i = t; i < NCLASS * NFEAT; i += 256) {
    int c = i / NFEAT, k = i % NFEAT;
    rwT[k * NCLASS + c] = res_w[i];
  }
#pragma unroll
  for (int it = 0; it < 16; ++it) {
    int i = t + it * 256;
    int r = i >> 5, kq = i & 31;
    int gr = R0 + r;
    float4 v = make_float4(0.f, 0.f, 0.f, 0.f);
    if (gr < N_NODES) v = *(const float4*)(x + (size_t)gr * NFEAT + kq * 4);
    int rw = r ^ ((kq & 7) << 2);
    xT[(kq * 4 + 0) * 128 + rw] = v.x;
    xT[(kq * 4 + 1) * 128 + rw] = v.y;
    xT[(kq * 4 + 2) * 128 + rw] = v.z;
    xT[(kq * 4 + 3) * 128 + rw] = v.w;
  }
  __syncthreads();
  int cg = t & 7, rg = t >> 3;
  int c0 = cg * 5, r0 = rg * 4;
  float acc[4][5] = {};
#pragma unroll 4
  for (int k = 0; k < NFEAT; ++k) {
    float4 xv = *(const float4*)&xT[k * 128 + (r0 ^ swz(k))];
    float xr[4] = {xv.x, xv.y, xv.z, xv.w};
    float wr[5];
#pragma unroll
    for (int c = 0; c < 5; ++c) wr[c] = rwT[k * NCLASS + c0 + c];
#pragma unroll
    for (int j = 0; j < 4; ++j)
#pragma unroll
      for (int c = 0; c < 5; ++c)
        acc[j][c] = fmaf(xr[j], wr[c], acc[j][c]);
  }
  float bb[5];
#pragma unroll
  for (int c = 0; c < 5; ++c) bb[c] = res_b[c0 + c];
#pragma unroll
  for (int j = 0; j < 4; ++j) {
    int gr = R0 + r0 + j;
    if (gr < N_NODES) {
#pragma unroll
      for (int c = 0; c < 5; ++c)
        res[(size_t)gr * NCLASS + c0 + c] = acc[j][c] + bb[c];
    }
  }
  // ---- fused bucket histogram (blocks < NCHUNK; reuses xT as int counters) ----
  if (blockIdx.x < NCHUNK) {
    __syncthreads();
    int* cnt = (int*)xT;
    for (int i = t; i < NBUCK; i += 256) cnt[i] = 0;
    __syncthreads();
    int e0 = blockIdx.x * CHUNK;
    int ecnt = min(CHUNK, N_EDGES - e0);
    for (int i = t; i < ecnt; i += 256)
      atomicAdd(&cnt[ei[e0 + i] >> 6], 1);
    __syncthreads();
    for (int i = t; i < NBUCK; i += 256)
      if (cnt[i]) atomicAdd(&bcnt[i], cnt[i]);
  }
}

// ------ Kernel C: scan buckets -> gptr; zero gfill -----------------------------
__global__ __launch_bounds__(256) void k_bscan(const int* __restrict__ bcnt,
    int* __restrict__ gptr, int* __restrict__ gfill) {
  __shared__ int psum[256];
  int t = threadIdx.x;
  int base = t * 4;
  int s[4];
#pragma unroll
  for (int j = 0; j < 4; ++j)
    s[j] = (base + j < NBUCK) ? bcnt[base + j] : 0;
  int local = s[0] + s[1] + s[2] + s[3];
  psum[t] = local;
  __syncthreads();
#pragma unroll
  for (int o = 1; o < 256; o <<= 1) {
    int v = (t >= o) ? psum[t - o] : 0;
    __syncthreads();
    psum[t] += v;
    __syncthreads();
  }
  int excl = psum[t] - local;
#pragma unroll
  for (int j = 0; j < 4; ++j) {
    if (base + j < NBUCK) gptr[base + j] = excl;
    excl += s[j];
  }
  if (t == 255) gptr[NBUCK] = psum[255];
  for (int i = t; i < NBUCK; i += 256) gfill[i] = 0;
}

// ------ Kernel D: staged bucket scatter (burst writes; payload = adj[e]) -------
__global__ __launch_bounds__(256) void k_bscatter(const int* __restrict__ ei,
    const float* __restrict__ adj, const int* __restrict__ gptr,
    int* __restrict__ gfill, uint2* __restrict__ edata) {
  __shared__ int cnt[NBUCK];
  __shared__ int off[NBUCK];
  __shared__ int gbase[NBUCK];
  __shared__ int po[NBUCK];
  __shared__ int psum[256];
  __shared__ uint2 stage[SCHUNK];   // 16 KB
  int t = threadIdx.x;
  int e0 = blockIdx.x * SCHUNK;
  int ecnt = min(SCHUNK, N_EDGES - e0);
  for (int i = t; i < NBUCK; i += 256) { cnt[i] = 0; po[i] = 0; }
  __syncthreads();
  for (int i = t; i < ecnt; i += 256)
    atomicAdd(&cnt[ei[e0 + i] >> 6], 1);
  __syncthreads();
  int base = t * 4;
  int s0 = (base < NBUCK) ? cnt[base] : 0;
  int s1 = (base + 1 < NBUCK) ? cnt[base + 1] : 0;
  int s2 = (base + 2 < NBUCK) ? cnt[base + 2] : 0;
  int s3 = (base + 3 < NBUCK) ? cnt[base + 3] : 0;
  int local = s0 + s1 + s2 + s3;
  psum[t] = local;
  __syncthreads();
#pragma unroll
  for (int o = 1; o < 256; o <<= 1) {
    int v = (t >= o) ? psum[t - o] : 0;
    __syncthreads();
    psum[t] += v;
    __syncthreads();
  }
  int excl = psum[t] - local;
  if (base < NBUCK) {
    off[base] = excl;
    if (s0 > 0) gbase[base] = gptr[base] + atomicAdd(&gfill[base], s0);
  }
  if (base + 1 < NBUCK) {
    off[base + 1] = excl + s0;
    if (s1 > 0) gbase[base + 1] = gptr[base + 1] + atomicAdd(&gfill[base + 1], s1);
  }
  if (base + 2 < NBUCK) {
    off[base + 2] = excl + s0 + s1;
    if (s2 > 0) gbase[base + 2] = gptr[base + 2] + atomicAdd(&gfill[base + 2], s2);
  }
  if (base + 3 < NBUCK) {
    off[base + 3] = excl + s0 + s1 + s2;
    if (s3 > 0) gbase[base + 3] = gptr[base + 3] + atomicAdd(&gfill[base + 3], s3);
  }
  __syncthreads();
  for (int i = t; i < ecnt; i += 256) {
    int e = e0 + i;
    int row = ei[e], col = ei[N_EDGES + e];
    int b = row >> 6;
    int pos = off[b] + atomicAdd(&po[b], 1);
    stage[pos] = make_uint2(((unsigned)b << 22) | ((unsigned)(row & 63) << 16) |
                            (unsigned)col, __float_as_uint(adj[e]));
  }
  __syncthreads();
  for (int i = t; i < ecnt; i += 256) {
    uint2 v = stage[i];
    int b = v.x >> 22;
    edata[(size_t)gbase[b] + (i - off[b])] = v;
  }
}

// ------ Kernel S: per-bucket CSR + edge weights (s_src via LDS) ----------------
__global__ __launch_bounds__(256) void k_csr(const uint2* __restrict__ edata,
    const int* __restrict__ gptr, const float* __restrict__ s_src,
    const float* __restrict__ s_dst, int* __restrict__ row_ptr,
    unsigned* __restrict__ ecsr) {
  __shared__ int lcnt[BROWS];
  __shared__ int lexcl[BROWS];
  __shared__ int lfill[BROWS];
  __shared__ float ssrc[BROWS];
  int t = threadIdx.x;
  int b = blockIdx.x;
  int es = gptr[b], ee = gptr[b + 1];
  if (t < BROWS) {
    lcnt[t] = 0; lfill[t] = 0;
    int gn = b * BROWS + t;
    ssrc[t] = (gn < N_NODES) ? s_src[gn] : 0.f;
  }
  __syncthreads();
  for (int i = es + t; i < ee; i += 256)
    atomicAdd(&lcnt[(edata[i].x >> 16) & 63u], 1);
  __syncthreads();
  if (t < 64) {  // wave 0: 64-lane inclusive scan
    int v = lcnt[t];
    int sc = v;
#pragma unroll
    for (int o = 1; o < 64; o <<= 1) {
      int u = __shfl_up(sc, o);
      if (t >= o) sc += u;
    }
    lexcl[t] = sc - v;
    int gn = b * BROWS + t;
    if (gn < N_NODES) row_ptr[gn] = es + sc - v;
  }
  if (b == NBUCK - 1 && t == 0) row_ptr[N_NODES] = ee;
  __syncthreads();
  for (int i = es + t; i < ee; i += 256) {
    uint2 v = edata[i];
    int rl = (v.x >> 16) & 63;
    int col = v.x & 0xffffu;
    float sc = ssrc[rl] + s_dst[col];
    sc = (sc > 0.f) ? sc : 0.2f * sc;                      // leaky_relu(0.2)
    float wv = __uint_as_float(v.y) / (1.f + __expf(-sc)); // sigmoid * adj
    int pos = es + lexcl[rl] + atomicAdd(&lfill[rl], 1);
    ecsr[pos] = bf16hi(wv) | (unsigned)col;
  }
}

// ------ Kernel E: agg1 edge-streaming + fused h2 = relu(agg)@W2 (bf16 out) -----
__global__ __launch_bounds__(256) void k_agg1(const unsigned* __restrict__ h1u,
    const unsigned* __restrict__ edata, const int* __restrict__ row_ptr,
    const float* __restrict__ W2, unsigned short* __restrict__ h2s) {
  __shared__ int rps[NPB + 1];
  __shared__ float accs[NPB][NHID];     // 4 KB
  __shared__ float W2s[NHID * NCLASS];  // 10 KB
  int t = threadIdx.x;
  int n0 = blockIdx.x * NPB;
  if (t <= NPB) rps[t] = row_ptr[min(n0 + t, N_NODES)];
  for (int i = t; i < NHID * NCLASS; i += 256) W2s[i] = W2[i];
  for (int i = t; i < NPB * NHID / 4; i += 256)
    ((float4*)&accs[0][0])[i] = make_float4(0.f, 0.f, 0.f, 0.f);
  __syncthreads();
  int e0 = rps[0], e1 = rps[NPB];
  int span = e1 - e0;
  int gid = t >> 5, s = t & 31;
  int chunk = (span + 7) >> 3;
  int es = e0 + gid * chunk;
  int ee = min(es + chunk, e1);
  if (es < ee) {
    int lo = 0, hi = NPB - 1;
    while (lo < hi) { int mid = (lo + hi) >> 1; if (rps[mid + 1] <= es) lo = mid + 1; else hi = mid; }
    int r = lo, nxt = rps[r + 1];
    float acc0 = 0.f, acc1 = 0.f;
    int e = es;
    while (e < ee) {
      int m = ee - e; if (m > 8) m = 8;
      unsigned ue = (s < m) ? edata[e + s] : 0u;   // one request per batch
      unsigned u[8], v[8];
#pragma unroll
      for (int i = 0; i < 8; ++i) u[i] = __shfl(ue, i, 32);
#pragma unroll
      for (int i = 0; i < 8; ++i) if (i < m) v[i] = h1u[(size_t)(u[i] & 0xffffu) * 32 + s];
#pragma unroll
      for (int i = 0; i < 8; ++i) if (i < m) {
        while (e + i >= nxt) {
          atomicAdd(&accs[r][2 * s], acc0);
          atomicAdd(&accs[r][2 * s + 1], acc1);
          acc0 = acc1 = 0.f; ++r; nxt = rps[r + 1];
        }
        float wv = hi16(u[i]);
        acc0 = fmaf(wv, lo16(v[i]), acc0);
        acc1 = fmaf(wv, hi16(v[i]), acc1);
      }
      e += m;
    }
    atomicAdd(&accs[r][2 * s], acc0);
    atomicAdd(&accs[r][2 * s + 1], acc1);
  }
  __syncthreads();
  // relu in place
  for (int i = t; i < NPB * NHID; i += 256)
    ((float*)accs)[i] = fmaxf(((float*)accs)[i], 0.f);
  __syncthreads();
  // h2 = relu_acc @ W2 (640 outputs, bf16 to stride-48 rows)
  for (int idx = t; idx < NPB * NCLASS; idx += 256) {
    int n = idx / NCLASS, c = idx % NCLASS;
    int gn = n0 + n;
    if (gn < N_NODES) {
      float sum = 0.f;
#pragma unroll 8
      for (int j = 0; j < NHID; ++j)
        sum = fmaf(accs[n][j], W2s[j * NCLASS + c], sum);
      h2s[(size_t)gn * H2STRIDE + c] = (unsigned short)(bf16hi(sum) >> 16);
    }
  }
}

// ------ Kernel F: agg2 edge-streaming (per-lane load + shfl) + res + LN --------
__global__ __launch_bounds__(256) void k_agg2(const unsigned short* __restrict__ h2s,
    const unsigned* __restrict__ edata, const int* __restrict__ row_ptr,
    const float* __restrict__ res, const float* __restrict__ ln_g,
    const float* __restrict__ ln_b, float* __restrict__ out) {
  __shared__ int rps[NPB + 1];
  __shared__ float accs[NPB][NCLASS];   // 2.5 KB
  int t = threadIdx.x;
  int n0 = blockIdx.x * NPB;
  if (t <= NPB) rps[t] = row_ptr[min(n0 + t, N_NODES)];
  for (int i = t; i < NPB * NCLASS; i += 256) ((float*)accs)[i] = 0.f;
  __syncthreads();
  int e0 = rps[0], e1 = rps[NPB];
  int span = e1 - e0;
  int gid = t >> 5, s = t & 31;
  int chunk = (span + 7) >> 3;
  int es = e0 + gid * chunk;
  int ee = min(es + chunk, e1);
  bool act = (s < 20);
  if (es < ee) {
    int lo = 0, hi = NPB - 1;
    while (lo < hi) { int mid = (lo + hi) >> 1; if (rps[mid + 1] <= es) lo = mid + 1; else hi = mid; }
    int r = lo, nxt = rps[r + 1];
    float acc0 = 0.f, acc1 = 0.f;
    int e = es;
    while (e < ee) {
      int m = ee - e; if (m > 8) m = 8;
      unsigned ue = (s < m) ? edata[e + s] : 0u;   // one request per batch
      unsigned u[8], v[8];
#pragma unroll
      for (int i = 0; i < 8; ++i) u[i] = __shfl(ue, i, 32);
#pragma unroll
      for (int i = 0; i < 8; ++i) {
        v[i] = 0u;
        if (i < m && act)
          v[i] = *(const unsigned*)(h2s + (size_t)(u[i] & 0xffffu) * H2STRIDE + 2 * s);
      }
#pragma unroll
      for (int i = 0; i < 8; ++i) if (i < m) {
        while (e + i >= nxt) {
          if (act) {
            atomicAdd(&accs[r][2 * s], acc0);
            atomicAdd(&accs[r][2 * s + 1], acc1);
          }
          acc0 = acc1 = 0.f; ++r; nxt = rps[r + 1];
        }
        float wv = hi16(u[i]);
        acc0 = fmaf(wv, lo16(v[i]), acc0);
        acc1 = fmaf(wv, hi16(v[i]), acc1);
      }
      e += m;
    }
    if (act) {
      atomicAdd(&accs[r][2 * s], acc0);
      atomicAdd(&accs[r][2 * s + 1], acc1);
    }
  }
  __syncthreads();
  int wave = t >> 6, lane = t & 63;
  for (int k = 0; k < NPB / 4; ++k) {
    int n = wave * (NPB / 4) + k;
    int gn = n0 + n;
    if (gn >= N_NODES) break;
    float y = 0.f;
    if (lane < NCLASS)
      y = fmaxf(accs[n][lane], 0.f) + res[(size_t)gn * NCLASS + lane];
    float s1 = y, s2 = y * y;
#pragma unroll
    for (int off = 1; off < 64; off <<= 1) {
      s1 += __shfl_xor(s1, off);
      s2 += __shfl_xor(s2, off);
    }
    float mu = s1 / (float)NCLASS;
    float var = s2 / (float)NCLASS - mu * mu;
    float inv = rsqrtf(var + LN_EPS);
    if (lane < NCLASS)
      out[(size_t)gn * NCLASS + lane] = (y - mu) * inv * ln_g[lane] + ln_b[lane];
  }
}

// -------------------------------------------------------------------------------
extern "C" void kernel_launch(void* const* d_in, const int* in_sizes, int n_in,
                              void* d_out, int out_size, void* d_ws, size_t ws_size,
                              hipStream_t stream) {
  const float* x     = (const float*)d_in[0];
  const int*   ei    = (const int*)  d_in[1];
  const float* adj   = (const float*)d_in[2];
  const float* W1    = (const float*)d_in[3];
  const float* a1    = (const float*)d_in[4];
  const float* W2    = (const float*)d_in[5];
  const float* res_w = (const float*)d_in[6];
  const float* res_b = (const float*)d_in[7];
  const float* ln_g  = (const float*)d_in[8];
  const float* ln_b  = (const float*)d_in[9];
  float* out = (float*)d_out;

  char* ws = (char*)d_ws;
  size_t off = 0;
  auto alloc = [&](size_t bytes) -> void* {
    void* p = (void*)(ws + off);
    off += (bytes + 255) & ~(size_t)255;
    return p;
  };

  unsigned*       h1u     = (unsigned*)alloc((size_t)N_NODES * 32 * 4);  // bf16x2
  float*          s_src   = (float*)alloc((size_t)N_NODES * 4);
  float*          s_dst   = (float*)alloc((size_t)N_NODES * 4);
  int*            bcnt    = (int*)alloc((size_t)NBUCK * 4);
  int*            gptr    = (int*)alloc((size_t)(NBUCK + 1) * 4);
  int*            gfill   = (int*)alloc((size_t)NBUCK * 4);
  int*            row_ptr = (int*)alloc((size_t)(N_NODES + 1) * 4);
  uint2*          edata   = (uint2*)alloc((size_t)N_EDGES * 8);
  unsigned*       ecsr    = (unsigned*)alloc((size_t)N_EDGES * 4);
  unsigned short* h2s     = (unsigned short*)alloc((size_t)N_NODES * H2STRIDE * 2);
  float*          res     = (float*)alloc((size_t)N_NODES * NCLASS * 4);
  (void)ws_size; (void)in_sizes; (void)n_in; (void)out_size;

  const int NBLK_H1  = (N_NODES + 63) / 64;              // 782
  const int NBLK_RES = (N_NODES + 127) / 128;            // 391
  const int NBLK_AGG = (N_NODES + NPB - 1) / NPB;        // 3125

  k_h1mm<<<NBLK_H1, 256, 0, stream>>>(x, W1, a1, h1u, s_src, s_dst, bcnt);
  k_resmm<<<NBLK_RES, 256, 0, stream>>>(x, res_w, res_b, res, ei, bcnt);
  k_bscan<<<1, 256, 0, stream>>>(bcnt, gptr, gfill);
  k_bscatter<<<SNCHUNK, 256, 0, stream>>>(ei, adj, gptr, gfill, edata);
  k_csr<<<NBUCK, 256, 0, stream>>>(edata, gptr, s_src, s_dst, row_ptr, ecsr);
  k_agg1<<<NBLK_AGG, 256, 0, stream>>>(h1u, ecsr, row_ptr, W2, h2s);
  k_agg2<<<NBLK_AGG, 256, 0, stream>>>(h2s, ecsr, row_ptr, res, ln_g, ln_b, out);
}

// Round 16
// 200.836 us; speedup vs baseline: 1.0237x; 1.0237x over previous
//
#include <hip/hip_runtime.h>
#include <math.h>

#define N_NODES 50000
#define N_EDGES 800000
#define NFEAT 128
#define NHID 64
#define NCLASS 40
#define LN_EPS 1e-5f
#define BROWS 64                                // rows per bucket
#define NBUCK ((N_NODES + BROWS - 1) / BROWS)   // 782
#define CHUNK 4096                              // edges per hist chunk
#define NCHUNK ((N_EDGES + CHUNK - 1) / CHUNK)  // 196
#define SCHUNK 2048                             // edges per scatter chunk
#define SNCHUNK ((N_EDGES + SCHUNK - 1) / SCHUNK) // 391
#define NPB 16                                  // nodes per agg block
#define H2ROWS 64
#define H2STRIDE 48                             // ushorts/row (96B, <=2 lines)

__device__ __forceinline__ int swz(int k) { return ((k >> 2) & 7) << 2; }

__device__ __forceinline__ unsigned packbf(float a, float b) {
  unsigned ua = __float_as_uint(a), ub = __float_as_uint(b);
  ua += 0x7fffu + ((ua >> 16) & 1u);
  ub += 0x7fffu + ((ub >> 16) & 1u);
  return (ua >> 16) | (ub & 0xffff0000u);
}
__device__ __forceinline__ unsigned bf16hi(float a) {
  unsigned u = __float_as_uint(a);
  u += 0x7fffu + ((u >> 16) & 1u);
  return u & 0xffff0000u;
}
__device__ __forceinline__ float lo16(unsigned v) { return __uint_as_float(v << 16); }
__device__ __forceinline__ float hi16(unsigned v) { return __uint_as_float(v & 0xffff0000u); }

// ------ Kernel A: h1 = x @ W1 (reg-blocked 4x4) + fused s_src/s_dst ------------
// block 0 also zeroes bcnt (stream order: completes before k_resmm's histogram)
__global__ __launch_bounds__(256) void k_h1mm(const float* __restrict__ x,
    const float* __restrict__ W1, const float* __restrict__ a1,
    unsigned* __restrict__ h1u, float* __restrict__ s_src, float* __restrict__ s_dst,
    int* __restrict__ bcnt) {
  __shared__ float xT[NFEAT * 64];    // 32 KB
  __shared__ float W1s[NFEAT * NHID]; // 32 KB
  int t = threadIdx.x;
  if (blockIdx.x == 0)
    for (int i = t; i < NBUCK; i += 256) bcnt[i] = 0;
  int R0 = blockIdx.x * 64;
  for (int i = t; i < NFEAT * NHID / 4; i += 256)
    ((float4*)W1s)[i] = ((const float4*)W1)[i];
#pragma unroll
  for (int it = 0; it < 8; ++it) {
    int i = t + it * 256;
    int r = i >> 5, kq = i & 31;
    int gr = R0 + r;
    float4 v = make_float4(0.f, 0.f, 0.f, 0.f);
    if (gr < N_NODES) v = *(const float4*)(x + (size_t)gr * NFEAT + kq * 4);
    int rw = r ^ ((kq & 7) << 2);
    xT[(kq * 4 + 0) * 64 + rw] = v.x;
    xT[(kq * 4 + 1) * 64 + rw] = v.y;
    xT[(kq * 4 + 2) * 64 + rw] = v.z;
    xT[(kq * 4 + 3) * 64 + rw] = v.w;
  }
  __syncthreads();
  int cg = t & 15, rg = t >> 4;
  int c0 = cg * 4, r0 = rg * 4;
  float acc[4][4] = {};
#pragma unroll 4
  for (int k = 0; k < NFEAT; ++k) {
    float4 xv = *(const float4*)&xT[k * 64 + (r0 ^ swz(k))];
    float4 wv = *(const float4*)&W1s[k * NHID + c0];
    float xr[4] = {xv.x, xv.y, xv.z, xv.w};
    float wr[4] = {wv.x, wv.y, wv.z, wv.w};
#pragma unroll
    for (int j = 0; j < 4; ++j)
#pragma unroll
      for (int c = 0; c < 4; ++c)
        acc[j][c] = fmaf(xr[j], wr[c], acc[j][c]);
  }
  float4 as = *(const float4*)(a1 + c0);
  float4 ad = *(const float4*)(a1 + NHID + c0);
  float asr[4] = {as.x, as.y, as.z, as.w};
  float adr[4] = {ad.x, ad.y, ad.z, ad.w};
  float ps[4], pd[4];
#pragma unroll
  for (int j = 0; j < 4; ++j) {
    int gr = R0 + r0 + j;
    if (gr < N_NODES) {
      uint2 pk;
      pk.x = packbf(acc[j][0], acc[j][1]);
      pk.y = packbf(acc[j][2], acc[j][3]);
      *(uint2*)&h1u[(size_t)gr * 32 + (c0 >> 1)] = pk;
    }
    float s = 0.f, d = 0.f;
#pragma unroll
    for (int c = 0; c < 4; ++c) {
      s = fmaf(acc[j][c], asr[c], s);
      d = fmaf(acc[j][c], adr[c], d);
    }
    ps[j] = s; pd[j] = d;
  }
#pragma unroll
  for (int j = 0; j < 4; ++j)
#pragma unroll
    for (int off = 1; off < 16; off <<= 1) {
      ps[j] += __shfl_xor(ps[j], off);
      pd[j] += __shfl_xor(pd[j], off);
    }
  if (cg == 0) {
#pragma unroll
    for (int j = 0; j < 4; ++j) {
      int gr = R0 + r0 + j;
      if (gr < N_NODES) { s_src[gr] = ps[j]; s_dst[gr] = pd[j]; }
    }
  }
}

// ------ Kernel R: res = x @ res_w^T + res_b (4x5) + fused bucket histogram -----
__global__ __launch_bounds__(256) void k_resmm(const float* __restrict__ x,
    const float* __restrict__ res_w, const float* __restrict__ res_b,
    float* __restrict__ res, const int* __restrict__ ei, int* __restrict__ bcnt) {
  __shared__ float xT[NFEAT * 128];     // 64 KB
  __shared__ float rwT[NFEAT * NCLASS]; // 20 KB
  int t = threadIdx.x;
  int R0 = blockIdx.x * 128;
  for (int i = t; i < NCLASS * NFEAT; i += 256) {
    int c = i / NFEAT, k = i % NFEAT;
    rwT[k * NCLASS + c] = res_w[i];
  }
#pragma unroll
  for (int it = 0; it < 16; ++it) {
    int i = t + it * 256;
    int r = i >> 5, kq = i & 31;
    int gr = R0 + r;
    float4 v = make_float4(0.f, 0.f, 0.f, 0.f);
    if (gr < N_NODES) v = *(const float4*)(x + (size_t)gr * NFEAT + kq * 4);
    int rw = r ^ ((kq & 7) << 2);
    xT[(kq * 4 + 0) * 128 + rw] = v.x;
    xT[(kq * 4 + 1) * 128 + rw] = v.y;
    xT[(kq * 4 + 2) * 128 + rw] = v.z;
    xT[(kq * 4 + 3) * 128 + rw] = v.w;
  }
  __syncthreads();
  int cg = t & 7, rg = t >> 3;
  int c0 = cg * 5, r0 = rg * 4;
  float acc[4][5] = {};
#pragma unroll 4
  for (int k = 0; k < NFEAT; ++k) {
    float4 xv = *(const float4*)&xT[k * 128 + (r0 ^ swz(k))];
    float xr[4] = {xv.x, xv.y, xv.z, xv.w};
    float wr[5];
#pragma unroll
    for (int c = 0; c < 5; ++c) wr[c] = rwT[k * NCLASS + c0 + c];
#pragma unroll
    for (int j = 0; j < 4; ++j)
#pragma unroll
      for (int c = 0; c < 5; ++c)
        acc[j][c] = fmaf(xr[j], wr[c], acc[j][c]);
  }
  float bb[5];
#pragma unroll
  for (int c = 0; c < 5; ++c) bb[c] = res_b[c0 + c];
#pragma unroll
  for (int j = 0; j < 4; ++j) {
    int gr = R0 + r0 + j;
    if (gr < N_NODES) {
#pragma unroll
      for (int c = 0; c < 5; ++c)
        res[(size_t)gr * NCLASS + c0 + c] = acc[j][c] + bb[c];
    }
  }
  // ---- fused bucket histogram (blocks < NCHUNK; reuses xT as int counters) ----
  if (blockIdx.x < NCHUNK) {
    __syncthreads();
    int* cnt = (int*)xT;
    for (int i = t; i < NBUCK; i += 256) cnt[i] = 0;
    __syncthreads();
    int e0 = blockIdx.x * CHUNK;
    int ecnt = min(CHUNK, N_EDGES - e0);
    for (int i = t; i < ecnt; i += 256)
      atomicAdd(&cnt[ei[e0 + i] >> 6], 1);
    __syncthreads();
    for (int i = t; i < NBUCK; i += 256)
      if (cnt[i]) atomicAdd(&bcnt[i], cnt[i]);
  }
}

// ------ Kernel C: scan buckets -> gptr; zero gfill -----------------------------
__global__ __launch_bounds__(256) void k_bscan(const int* __restrict__ bcnt,
    int* __restrict__ gptr, int* __restrict__ gfill) {
  __shared__ int psum[256];
  int t = threadIdx.x;
  int base = t * 4;
  int s[4];
#pragma unroll
  for (int j = 0; j < 4; ++j)
    s[j] = (base + j < NBUCK) ? bcnt[base + j] : 0;
  int local = s[0] + s[1] + s[2] + s[3];
  psum[t] = local;
  __syncthreads();
#pragma unroll
  for (int o = 1; o < 256; o <<= 1) {
    int v = (t >= o) ? psum[t - o] : 0;
    __syncthreads();
    psum[t] += v;
    __syncthreads();
  }
  int excl = psum[t] - local;
#pragma unroll
  for (int j = 0; j < 4; ++j) {
    if (base + j < NBUCK) gptr[base + j] = excl;
    excl += s[j];
  }
  if (t == 255) gptr[NBUCK] = psum[255];
  for (int i = t; i < NBUCK; i += 256) gfill[i] = 0;
}

// ------ Kernel D: staged bucket scatter (burst writes; payload = adj[e]) -------
__global__ __launch_bounds__(256) void k_bscatter(const int* __restrict__ ei,
    const float* __restrict__ adj, const int* __restrict__ gptr,
    int* __restrict__ gfill, uint2* __restrict__ edata) {
  __shared__ int cnt[NBUCK];
  __shared__ int off[NBUCK];
  __shared__ int gbase[NBUCK];
  __shared__ int po[NBUCK];
  __shared__ int psum[256];
  __shared__ uint2 stage[SCHUNK];   // 16 KB
  int t = threadIdx.x;
  int e0 = blockIdx.x * SCHUNK;
  int ecnt = min(SCHUNK, N_EDGES - e0);
  for (int i = t; i < NBUCK; i += 256) { cnt[i] = 0; po[i] = 0; }
  __syncthreads();
  for (int i = t; i < ecnt; i += 256)
    atomicAdd(&cnt[ei[e0 + i] >> 6], 1);
  __syncthreads();
  int base = t * 4;
  int s0 = (base < NBUCK) ? cnt[base] : 0;
  int s1 = (base + 1 < NBUCK) ? cnt[base + 1] : 0;
  int s2 = (base + 2 < NBUCK) ? cnt[base + 2] : 0;
  int s3 = (base + 3 < NBUCK) ? cnt[base + 3] : 0;
  int local = s0 + s1 + s2 + s3;
  psum[t] = local;
  __syncthreads();
#pragma unroll
  for (int o = 1; o < 256; o <<= 1) {
    int v = (t >= o) ? psum[t - o] : 0;
    __syncthreads();
    psum[t] += v;
    __syncthreads();
  }
  int excl = psum[t] - local;
  if (base < NBUCK) {
    off[base] = excl;
    if (s0 > 0) gbase[base] = gptr[base] + atomicAdd(&gfill[base], s0);
  }
  if (base + 1 < NBUCK) {
    off[base + 1] = excl + s0;
    if (s1 > 0) gbase[base + 1] = gptr[base + 1] + atomicAdd(&gfill[base + 1], s1);
  }
  if (base + 2 < NBUCK) {
    off[base + 2] = excl + s0 + s1;
    if (s2 > 0) gbase[base + 2] = gptr[base + 2] + atomicAdd(&gfill[base + 2], s2);
  }
  if (base + 3 < NBUCK) {
    off[base + 3] = excl + s0 + s1 + s2;
    if (s3 > 0) gbase[base + 3] = gptr[base + 3] + atomicAdd(&gfill[base + 3], s3);
  }
  __syncthreads();
  for (int i = t; i < ecnt; i += 256) {
    int e = e0 + i;
    int row = ei[e], col = ei[N_EDGES + e];
    int b = row >> 6;
    int pos = off[b] + atomicAdd(&po[b], 1);
    stage[pos] = make_uint2(((unsigned)b << 22) | ((unsigned)(row & 63) << 16) |
                            (unsigned)col, __float_as_uint(adj[e]));
  }
  __syncthreads();
  for (int i = t; i < ecnt; i += 256) {
    uint2 v = stage[i];
    int b = v.x >> 22;
    edata[(size_t)gbase[b] + (i - off[b])] = v;
  }
}

// ------ Kernel S: per-bucket CSR + edge weights (s_src via LDS) ----------------
__global__ __launch_bounds__(256) void k_csr(const uint2* __restrict__ edata,
    const int* __restrict__ gptr, const float* __restrict__ s_src,
    const float* __restrict__ s_dst, int* __restrict__ row_ptr,
    unsigned* __restrict__ ecsr) {
  __shared__ int lcnt[BROWS];
  __shared__ int lexcl[BROWS];
  __shared__ int lfill[BROWS];
  __shared__ float ssrc[BROWS];
  int t = threadIdx.x;
  int b = blockIdx.x;
  int es = gptr[b], ee = gptr[b + 1];
  if (t < BROWS) {
    lcnt[t] = 0; lfill[t] = 0;
    int gn = b * BROWS + t;
    ssrc[t] = (gn < N_NODES) ? s_src[gn] : 0.f;
  }
  __syncthreads();
  for (int i = es + t; i < ee; i += 256)
    atomicAdd(&lcnt[(edata[i].x >> 16) & 63u], 1);
  __syncthreads();
  if (t < 64) {  // wave 0: 64-lane inclusive scan
    int v = lcnt[t];
    int sc = v;
#pragma unroll
    for (int o = 1; o < 64; o <<= 1) {
      int u = __shfl_up(sc, o);
      if (t >= o) sc += u;
    }
    lexcl[t] = sc - v;
    int gn = b * BROWS + t;
    if (gn < N_NODES) row_ptr[gn] = es + sc - v;
  }
  if (b == NBUCK - 1 && t == 0) row_ptr[N_NODES] = ee;
  __syncthreads();
  for (int i = es + t; i < ee; i += 256) {
    uint2 v = edata[i];
    int rl = (v.x >> 16) & 63;
    int col = v.x & 0xffffu;
    float sc = ssrc[rl] + s_dst[col];
    sc = (sc > 0.f) ? sc : 0.2f * sc;                      // leaky_relu(0.2)
    float wv = __uint_as_float(v.y) / (1.f + __expf(-sc)); // sigmoid * adj
    int pos = es + lexcl[rl] + atomicAdd(&lfill[rl], 1);
    ecsr[pos] = bf16hi(wv) | (unsigned)col;
  }
}

// ------ Kernel E: agg1 edge-streaming (per-lane edata load + shfl bcast) -------
__global__ __launch_bounds__(256) void k_agg1(const unsigned* __restrict__ h1u,
    const unsigned* __restrict__ edata, const int* __restrict__ row_ptr,
    unsigned* __restrict__ h1o) {
  __shared__ int rps[NPB + 1];
  __shared__ float accs[NPB][NHID];   // 4 KB
  int t = threadIdx.x;
  int n0 = blockIdx.x * NPB;
  if (t <= NPB) rps[t] = row_ptr[min(n0 + t, N_NODES)];
  for (int i = t; i < NPB * NHID / 4; i += 256)
    ((float4*)&accs[0][0])[i] = make_float4(0.f, 0.f, 0.f, 0.f);
  __syncthreads();
  int e0 = rps[0], e1 = rps[NPB];
  int span = e1 - e0;
  int gid = t >> 5, s = t & 31;
  int chunk = (span + 7) >> 3;
  int es = e0 + gid * chunk;
  int ee = min(es + chunk, e1);
  if (es < ee) {
    int lo = 0, hi = NPB - 1;
    while (lo < hi) { int mid = (lo + hi) >> 1; if (rps[mid + 1] <= es) lo = mid + 1; else hi = mid; }
    int r = lo, nxt = rps[r + 1];
    float acc0 = 0.f, acc1 = 0.f;
    int e = es;
    while (e < ee) {
      int m = ee - e; if (m > 8) m = 8;
      unsigned ue = (s < m) ? edata[e + s] : 0u;   // one request per batch
      unsigned u[8], v[8];
#pragma unroll
      for (int i = 0; i < 8; ++i) u[i] = __shfl(ue, i, 32);
#pragma unroll
      for (int i = 0; i < 8; ++i) if (i < m) v[i] = h1u[(size_t)(u[i] & 0xffffu) * 32 + s];
#pragma unroll
      for (int i = 0; i < 8; ++i) if (i < m) {
        while (e + i >= nxt) {
          atomicAdd(&accs[r][2 * s], acc0);
          atomicAdd(&accs[r][2 * s + 1], acc1);
          acc0 = acc1 = 0.f; ++r; nxt = rps[r + 1];
        }
        float wv = hi16(u[i]);
        acc0 = fmaf(wv, lo16(v[i]), acc0);
        acc1 = fmaf(wv, hi16(v[i]), acc1);
      }
      e += m;
    }
    atomicAdd(&accs[r][2 * s], acc0);
    atomicAdd(&accs[r][2 * s + 1], acc1);
  }
  __syncthreads();
  for (int i = t; i < NPB * 32; i += 256) {
    int n = i >> 5, c = i & 31;
    int gn = n0 + n;
    if (gn < N_NODES)
      h1o[(size_t)gn * 32 + c] =
          packbf(fmaxf(accs[n][2 * c], 0.f), fmaxf(accs[n][2 * c + 1], 0.f));
  }
}

// ------ Kernel G: h2 = h1o @ W2 (bf16 in, bf16 out, stride 48 ushorts) ---------
__global__ __launch_bounds__(256) void k_h2mm(const unsigned* __restrict__ h1o,
    const float* __restrict__ W2, unsigned short* __restrict__ h2s) {
  __shared__ unsigned xs[H2ROWS * 32];  // swizzled, 8 KB
  __shared__ float W2s[NHID * NCLASS];  // 10 KB
  int t = threadIdx.x;
  int R0 = blockIdx.x * H2ROWS;
  for (int i = t; i < NHID * NCLASS; i += 256) W2s[i] = W2[i];
  for (int i = t; i < H2ROWS * 32; i += 256) {
    int r = i >> 5, ku = i & 31;
    int gr = R0 + r;
    unsigned v = (gr < N_NODES) ? h1o[(size_t)gr * 32 + ku] : 0u;
    xs[r * 32 + (ku ^ (r & 31))] = v;
  }
  __syncthreads();
  int q = t & 31, cg = t >> 5;
  int c0 = cg * 5;
  float acc[2][5] = {};
#pragma unroll 8
  for (int ku = 0; ku < 32; ++ku) {
    unsigned ua = xs[q * 32 + (ku ^ q)];
    unsigned ub = xs[(q + 32) * 32 + (ku ^ q)];
    float a0 = lo16(ua), a1 = hi16(ua);
    float b0 = lo16(ub), b1 = hi16(ub);
#pragma unroll
    for (int c = 0; c < 5; ++c) {
      float w0 = W2s[(2 * ku) * NCLASS + c0 + c];
      float w1 = W2s[(2 * ku + 1) * NCLASS + c0 + c];
      acc[0][c] = fmaf(a0, w0, acc[0][c]);
      acc[0][c] = fmaf(a1, w1, acc[0][c]);
      acc[1][c] = fmaf(b0, w0, acc[1][c]);
      acc[1][c] = fmaf(b1, w1, acc[1][c]);
    }
  }
#pragma unroll
  for (int j = 0; j < 2; ++j) {
    int gr = R0 + q + j * 32;
    if (gr < N_NODES) {
#pragma unroll
      for (int c = 0; c < 5; ++c)
        h2s[(size_t)gr * H2STRIDE + c0 + c] = (unsigned short)(bf16hi(acc[j][c]) >> 16);
    }
  }
}

// ------ Kernel F: agg2 edge-streaming (per-lane load + shfl) + res + LN --------
__global__ __launch_bounds__(256) void k_agg2(const unsigned short* __restrict__ h2s,
    const unsigned* __restrict__ edata, const int* __restrict__ row_ptr,
    const float* __restrict__ res, const float* __restrict__ ln_g,
    const float* __restrict__ ln_b, float* __restrict__ out) {
  __shared__ int rps[NPB + 1];
  __shared__ float accs[NPB][NCLASS];   // 2.5 KB
  int t = threadIdx.x;
  int n0 = blockIdx.x * NPB;
  if (t <= NPB) rps[t] = row_ptr[min(n0 + t, N_NODES)];
  for (int i = t; i < NPB * NCLASS; i += 256) ((float*)accs)[i] = 0.f;
  __syncthreads();
  int e0 = rps[0], e1 = rps[NPB];
  int span = e1 - e0;
  int gid = t >> 5, s = t & 31;
  int chunk = (span + 7) >> 3;
  int es = e0 + gid * chunk;
  int ee = min(es + chunk, e1);
  bool act = (s < 20);
  if (es < ee) {
    int lo = 0, hi = NPB - 1;
    while (lo < hi) { int mid = (lo + hi) >> 1; if (rps[mid + 1] <= es) lo = mid + 1; else hi = mid; }
    int r = lo, nxt = rps[r + 1];
    float acc0 = 0.f, acc1 = 0.f;
    int e = es;
    while (e < ee) {
      int m = ee - e; if (m > 8) m = 8;
      unsigned ue = (s < m) ? edata[e + s] : 0u;   // one request per batch
      unsigned u[8], v[8];
#pragma unroll
      for (int i = 0; i < 8; ++i) u[i] = __shfl(ue, i, 32);
#pragma unroll
      for (int i = 0; i < 8; ++i) {
        v[i] = 0u;
        if (i < m && act)
          v[i] = *(const unsigned*)(h2s + (size_t)(u[i] & 0xffffu) * H2STRIDE + 2 * s);
      }
#pragma unroll
      for (int i = 0; i < 8; ++i) if (i < m) {
        while (e + i >= nxt) {
          if (act) {
            atomicAdd(&accs[r][2 * s], acc0);
            atomicAdd(&accs[r][2 * s + 1], acc1);
          }
          acc0 = acc1 = 0.f; ++r; nxt = rps[r + 1];
        }
        float wv = hi16(u[i]);
        acc0 = fmaf(wv, lo16(v[i]), acc0);
        acc1 = fmaf(wv, hi16(v[i]), acc1);
      }
      e += m;
    }
    if (act) {
      atomicAdd(&accs[r][2 * s], acc0);
      atomicAdd(&accs[r][2 * s + 1], acc1);
    }
  }
  __syncthreads();
  int wave = t >> 6, lane = t & 63;
  for (int k = 0; k < NPB / 4; ++k) {
    int n = wave * (NPB / 4) + k;
    int gn = n0 + n;
    if (gn >= N_NODES) break;
    float y = 0.f;
    if (lane < NCLASS)
      y = fmaxf(accs[n][lane], 0.f) + res[(size_t)gn * NCLASS + lane];
    float s1 = y, s2 = y * y;
#pragma unroll
    for (int off = 1; off < 64; off <<= 1) {
      s1 += __shfl_xor(s1, off);
      s2 += __shfl_xor(s2, off);
    }
    float mu = s1 / (float)NCLASS;
    float var = s2 / (float)NCLASS - mu * mu;
    float inv = rsqrtf(var + LN_EPS);
    if (lane < NCLASS)
      out[(size_t)gn * NCLASS + lane] = (y - mu) * inv * ln_g[lane] + ln_b[lane];
  }
}

// -------------------------------------------------------------------------------
extern "C" void kernel_launch(void* const* d_in, const int* in_sizes, int n_in,
                              void* d_out, int out_size, void* d_ws, size_t ws_size,
                              hipStream_t stream) {
  const float* x     = (const float*)d_in[0];
  const int*   ei    = (const int*)  d_in[1];
  const float* adj   = (const float*)d_in[2];
  const float* W1    = (const float*)d_in[3];
  const float* a1    = (const float*)d_in[4];
  const float* W2    = (const float*)d_in[5];
  const float* res_w = (const float*)d_in[6];
  const float* res_b = (const float*)d_in[7];
  const float* ln_g  = (const float*)d_in[8];
  const float* ln_b  = (const float*)d_in[9];
  float* out = (float*)d_out;

  char* ws = (char*)d_ws;
  size_t off = 0;
  auto alloc = [&](size_t bytes) -> void* {
    void* p = (void*)(ws + off);
    off += (bytes + 255) & ~(size_t)255;
    return p;
  };

  unsigned*       h1u     = (unsigned*)alloc((size_t)N_NODES * 32 * 4);  // bf16x2
  float*          s_src   = (float*)alloc((size_t)N_NODES * 4);
  float*          s_dst   = (float*)alloc((size_t)N_NODES * 4);
  int*            bcnt    = (int*)alloc((size_t)NBUCK * 4);
  int*            gptr    = (int*)alloc((size_t)(NBUCK + 1) * 4);
  int*            gfill   = (int*)alloc((size_t)NBUCK * 4);
  int*            row_ptr = (int*)alloc((size_t)(N_NODES + 1) * 4);
  uint2*          edata   = (uint2*)alloc((size_t)N_EDGES * 8);
  unsigned*       ecsr    = (unsigned*)alloc((size_t)N_EDGES * 4);
  unsigned*       h1o     = (unsigned*)alloc((size_t)N_NODES * 32 * 4);  // bf16x2
  unsigned short* h2s     = (unsigned short*)alloc((size_t)N_NODES * H2STRIDE * 2);
  float*          res     = (float*)alloc((size_t)N_NODES * NCLASS * 4);
  (void)ws_size; (void)in_sizes; (void)n_in; (void)out_size;

  const int NBLK_H1  = (N_NODES + 63) / 64;              // 782
  const int NBLK_RES = (N_NODES + 127) / 128;            // 391
  const int NBLK_H2  = (N_NODES + H2ROWS - 1) / H2ROWS;  // 782
  const int NBLK_AGG = (N_NODES + NPB - 1) / NPB;        // 3125

  k_h1mm<<<NBLK_H1, 256, 0, stream>>>(x, W1, a1, h1u, s_src, s_dst, bcnt);
  k_resmm<<<NBLK_RES, 256, 0, stream>>>(x, res_w, res_b, res, ei, bcnt);
  k_bscan<<<1, 256, 0, stream>>>(bcnt, gptr, gfill);
  k_bscatter<<<SNCHUNK, 256, 0, stream>>>(ei, adj, gptr, gfill, edata);
  k_csr<<<NBUCK, 256, 0, stream>>>(edata, gptr, s_src, s_dst, row_ptr, ecsr);
  k_agg1<<<NBLK_AGG, 256, 0, stream>>>(h1u, ecsr, row_ptr, h1o);
  k_h2mm<<<NBLK_H2, 256, 0, stream>>>(h1o, W2, h2s);
  k_agg2<<<NBLK_AGG, 256, 0, stream>>>(h2s, ecsr, row_ptr, res, ln_g, ln_b, out);
}

// Round 17
// 181.467 us; speedup vs baseline: 1.1329x; 1.1067x over previous
//
#include <hip/hip_runtime.h>
#include <math.h>

#define N_NODES 50000
#define N_EDGES 800000
#define NFEAT 128
#define NHID 64
#define NCLASS 40
#define LN_EPS 1e-5f
#define BROWS 64                                // rows per bucket
#define NBUCK ((N_NODES + BROWS - 1) / BROWS)   // 782
#define CHUNK 4096                              // edges per chunk
#define NCHUNK ((N_EDGES + CHUNK - 1) / CHUNK)  // 196
#define NPB 16                                  // nodes per agg block
#define H2ROWS 64
#define H2STRIDE 48                             // ushorts/row (96B, <=2 lines)

__device__ __forceinline__ int swz(int k) { return ((k >> 2) & 7) << 2; }

__device__ __forceinline__ unsigned packbf(float a, float b) {
  unsigned ua = __float_as_uint(a), ub = __float_as_uint(b);
  ua += 0x7fffu + ((ua >> 16) & 1u);
  ub += 0x7fffu + ((ub >> 16) & 1u);
  return (ua >> 16) | (ub & 0xffff0000u);
}
__device__ __forceinline__ unsigned bf16hi(float a) {
  unsigned u = __float_as_uint(a);
  u += 0x7fffu + ((u >> 16) & 1u);
  return u & 0xffff0000u;
}
__device__ __forceinline__ float lo16(unsigned v) { return __uint_as_float(v << 16); }
__device__ __forceinline__ float hi16(unsigned v) { return __uint_as_float(v & 0xffff0000u); }

// ------ Kernel A: h1 = x @ W1 (reg-blocked 4x4) + fused s_src/s_dst ------------
// block 0 also zeroes bcnt (stream order: completes before k_resmm's histogram)
__global__ __launch_bounds__(256) void k_h1mm(const float* __restrict__ x,
    const float* __restrict__ W1, const float* __restrict__ a1,
    unsigned* __restrict__ h1u, float* __restrict__ s_src, float* __restrict__ s_dst,
    int* __restrict__ bcnt) {
  __shared__ float xT[NFEAT * 64];    // 32 KB
  __shared__ float W1s[NFEAT * NHID]; // 32 KB
  int t = threadIdx.x;
  if (blockIdx.x == 0)
    for (int i = t; i < NBUCK; i += 256) bcnt[i] = 0;
  int R0 = blockIdx.x * 64;
  for (int i = t; i < NFEAT * NHID / 4; i += 256)
    ((float4*)W1s)[i] = ((const float4*)W1)[i];
#pragma unroll
  for (int it = 0; it < 8; ++it) {
    int i = t + it * 256;
    int r = i >> 5, kq = i & 31;
    int gr = R0 + r;
    float4 v = make_float4(0.f, 0.f, 0.f, 0.f);
    if (gr < N_NODES) v = *(const float4*)(x + (size_t)gr * NFEAT + kq * 4);
    int rw = r ^ ((kq & 7) << 2);
    xT[(kq * 4 + 0) * 64 + rw] = v.x;
    xT[(kq * 4 + 1) * 64 + rw] = v.y;
    xT[(kq * 4 + 2) * 64 + rw] = v.z;
    xT[(kq * 4 + 3) * 64 + rw] = v.w;
  }
  __syncthreads();
  int cg = t & 15, rg = t >> 4;
  int c0 = cg * 4, r0 = rg * 4;
  float acc[4][4] = {};
#pragma unroll 4
  for (int k = 0; k < NFEAT; ++k) {
    float4 xv = *(const float4*)&xT[k * 64 + (r0 ^ swz(k))];
    float4 wv = *(const float4*)&W1s[k * NHID + c0];
    float xr[4] = {xv.x, xv.y, xv.z, xv.w};
    float wr[4] = {wv.x, wv.y, wv.z, wv.w};
#pragma unroll
    for (int j = 0; j < 4; ++j)
#pragma unroll
      for (int c = 0; c < 4; ++c)
        acc[j][c] = fmaf(xr[j], wr[c], acc[j][c]);
  }
  float4 as = *(const float4*)(a1 + c0);
  float4 ad = *(const float4*)(a1 + NHID + c0);
  float asr[4] = {as.x, as.y, as.z, as.w};
  float adr[4] = {ad.x, ad.y, ad.z, ad.w};
  float ps[4], pd[4];
#pragma unroll
  for (int j = 0; j < 4; ++j) {
    int gr = R0 + r0 + j;
    if (gr < N_NODES) {
      uint2 pk;
      pk.x = packbf(acc[j][0], acc[j][1]);
      pk.y = packbf(acc[j][2], acc[j][3]);
      *(uint2*)&h1u[(size_t)gr * 32 + (c0 >> 1)] = pk;
    }
    float s = 0.f, d = 0.f;
#pragma unroll
    for (int c = 0; c < 4; ++c) {
      s = fmaf(acc[j][c], asr[c], s);
      d = fmaf(acc[j][c], adr[c], d);
    }
    ps[j] = s; pd[j] = d;
  }
#pragma unroll
  for (int j = 0; j < 4; ++j)
#pragma unroll
    for (int off = 1; off < 16; off <<= 1) {
      ps[j] += __shfl_xor(ps[j], off);
      pd[j] += __shfl_xor(pd[j], off);
    }
  if (cg == 0) {
#pragma unroll
    for (int j = 0; j < 4; ++j) {
      int gr = R0 + r0 + j;
      if (gr < N_NODES) { s_src[gr] = ps[j]; s_dst[gr] = pd[j]; }
    }
  }
}

// ------ Kernel R: res = x @ res_w^T + res_b (4x5) + histogram w/ chunk bases ---
__global__ __launch_bounds__(256) void k_resmm(const float* __restrict__ x,
    const float* __restrict__ res_w, const float* __restrict__ res_b,
    float* __restrict__ res, const int* __restrict__ ei, int* __restrict__ bcnt,
    int* __restrict__ ccnt, int* __restrict__ cbase) {
  __shared__ float xT[NFEAT * 128];     // 64 KB
  __shared__ float rwT[NFEAT * NCLASS]; // 20 KB
  int t = threadIdx.x;
  int R0 = blockIdx.x * 128;
  for (int i = t; i < NCLASS * NFEAT; i += 256) {
    int c = i / NFEAT, k = i % NFEAT;
    rwT[k * NCLASS + c] = res_w[i];
  }
#pragma unroll
  for (int it = 0; it < 16; ++it) {
    int i = t + it * 256;
    int r = i >> 5, kq = i & 31;
    int gr = R0 + r;
    float4 v = make_float4(0.f, 0.f, 0.f, 0.f);
    if (gr < N_NODES) v = *(const float4*)(x + (size_t)gr * NFEAT + kq * 4);
    int rw = r ^ ((kq & 7) << 2);
    xT[(kq * 4 + 0) * 128 + rw] = v.x;
    xT[(kq * 4 + 1) * 128 + rw] = v.y;
    xT[(kq * 4 + 2) * 128 + rw] = v.z;
    xT[(kq * 4 + 3) * 128 + rw] = v.w;
  }
  __syncthreads();
  int cg = t & 7, rg = t >> 3;
  int c0 = cg * 5, r0 = rg * 4;
  float acc[4][5] = {};
#pragma unroll 4
  for (int k = 0; k < NFEAT; ++k) {
    float4 xv = *(const float4*)&xT[k * 128 + (r0 ^ swz(k))];
    float xr[4] = {xv.x, xv.y, xv.z, xv.w};
    float wr[5];
#pragma unroll
    for (int c = 0; c < 5; ++c) wr[c] = rwT[k * NCLASS + c0 + c];
#pragma unroll
    for (int j = 0; j < 4; ++j)
#pragma unroll
      for (int c = 0; c < 5; ++c)
        acc[j][c] = fmaf(xr[j], wr[c], acc[j][c]);
  }
  float bb[5];
#pragma unroll
  for (int c = 0; c < 5; ++c) bb[c] = res_b[c0 + c];
#pragma unroll
  for (int j = 0; j < 4; ++j) {
    int gr = R0 + r0 + j;
    if (gr < N_NODES) {
#pragma unroll
      for (int c = 0; c < 5; ++c)
        res[(size_t)gr * NCLASS + c0 + c] = acc[j][c] + bb[c];
    }
  }
  // ---- fused bucket histogram: per-chunk counts + global reservation ----------
  if (blockIdx.x < NCHUNK) {
    __syncthreads();
    int* cnt = (int*)xT;
    for (int i = t; i < NBUCK; i += 256) cnt[i] = 0;
    __syncthreads();
    int e0 = blockIdx.x * CHUNK;
    int ecnt = min(CHUNK, N_EDGES - e0);
    for (int i = t; i < ecnt; i += 256)
      atomicAdd(&cnt[ei[e0 + i] >> 6], 1);
    __syncthreads();
    for (int i = t; i < NBUCK; i += 256) {
      int c = cnt[i];
      int base = (c > 0) ? atomicAdd(&bcnt[i], c) : atomicAdd(&bcnt[i], 0);
      ccnt[blockIdx.x * NBUCK + i] = c;
      cbase[blockIdx.x * NBUCK + i] = base;
    }
  }
}

// ------ Kernel C: scan buckets -> gptr -----------------------------------------
__global__ __launch_bounds__(256) void k_bscan(const int* __restrict__ bcnt,
    int* __restrict__ gptr) {
  __shared__ int psum[256];
  int t = threadIdx.x;
  int base = t * 4;
  int s[4];
#pragma unroll
  for (int j = 0; j < 4; ++j)
    s[j] = (base + j < NBUCK) ? bcnt[base + j] : 0;
  int local = s[0] + s[1] + s[2] + s[3];
  psum[t] = local;
  __syncthreads();
#pragma unroll
  for (int o = 1; o < 256; o <<= 1) {
    int v = (t >= o) ? psum[t - o] : 0;
    __syncthreads();
    psum[t] += v;
    __syncthreads();
  }
  int excl = psum[t] - local;
#pragma unroll
  for (int j = 0; j < 4; ++j) {
    if (base + j < NBUCK) gptr[base + j] = excl;
    excl += s[j];
  }
  if (t == 255) gptr[NBUCK] = psum[255];
}

// ------ Kernel D: bucket scatter, single edge pass (bases precomputed) ---------
__global__ __launch_bounds__(256) void k_bscatter(const int* __restrict__ ei,
    const float* __restrict__ adj, const int* __restrict__ gptr,
    const int* __restrict__ ccnt, const int* __restrict__ cbase,
    uint2* __restrict__ edata) {
  __shared__ int cnt[NBUCK];
  __shared__ int off[NBUCK];
  __shared__ int gbase[NBUCK];
  __shared__ int po[NBUCK];
  __shared__ int psum[256];
  __shared__ uint2 stage[CHUNK];   // 32 KB
  int t = threadIdx.x;
  int cix = blockIdx.x;
  int e0 = cix * CHUNK;
  int ecnt = min(CHUNK, N_EDGES - e0);
  for (int i = t; i < NBUCK; i += 256) {
    int c = ccnt[cix * NBUCK + i];
    cnt[i] = c;
    gbase[i] = gptr[i] + cbase[cix * NBUCK + i];
    po[i] = 0;
  }
  __syncthreads();
  int base = t * 4;
  int s0 = (base < NBUCK) ? cnt[base] : 0;
  int s1 = (base + 1 < NBUCK) ? cnt[base + 1] : 0;
  int s2 = (base + 2 < NBUCK) ? cnt[base + 2] : 0;
  int s3 = (base + 3 < NBUCK) ? cnt[base + 3] : 0;
  int local = s0 + s1 + s2 + s3;
  psum[t] = local;
  __syncthreads();
#pragma unroll
  for (int o = 1; o < 256; o <<= 1) {
    int v = (t >= o) ? psum[t - o] : 0;
    __syncthreads();
    psum[t] += v;
    __syncthreads();
  }
  int excl = psum[t] - local;
  if (base < NBUCK)     off[base]     = excl;
  if (base + 1 < NBUCK) off[base + 1] = excl + s0;
  if (base + 2 < NBUCK) off[base + 2] = excl + s0 + s1;
  if (base + 3 < NBUCK) off[base + 3] = excl + s0 + s1 + s2;
  __syncthreads();
  for (int i = t; i < ecnt; i += 256) {
    int e = e0 + i;
    int row = ei[e], col = ei[N_EDGES + e];
    int b = row >> 6;
    int pos = off[b] + atomicAdd(&po[b], 1);
    stage[pos] = make_uint2(((unsigned)b << 22) | ((unsigned)(row & 63) << 16) |
                            (unsigned)col, __float_as_uint(adj[e]));
  }
  __syncthreads();
  for (int i = t; i < ecnt; i += 256) {
    uint2 v = stage[i];
    int b = v.x >> 22;
    edata[(size_t)gbase[b] + (i - off[b])] = v;
  }
}

// ------ Kernel S: per-bucket CSR + edge weights (s_src via LDS) ----------------
__global__ __launch_bounds__(256) void k_csr(const uint2* __restrict__ edata,
    const int* __restrict__ gptr, const float* __restrict__ s_src,
    const float* __restrict__ s_dst, int* __restrict__ row_ptr,
    unsigned* __restrict__ ecsr) {
  __shared__ int lcnt[BROWS];
  __shared__ int lexcl[BROWS];
  __shared__ int lfill[BROWS];
  __shared__ float ssrc[BROWS];
  int t = threadIdx.x;
  int b = blockIdx.x;
  int es = gptr[b], ee = gptr[b + 1];
  if (t < BROWS) {
    lcnt[t] = 0; lfill[t] = 0;
    int gn = b * BROWS + t;
    ssrc[t] = (gn < N_NODES) ? s_src[gn] : 0.f;
  }
  __syncthreads();
  for (int i = es + t; i < ee; i += 256)
    atomicAdd(&lcnt[(edata[i].x >> 16) & 63u], 1);
  __syncthreads();
  if (t < 64) {  // wave 0: 64-lane inclusive scan
    int v = lcnt[t];
    int sc = v;
#pragma unroll
    for (int o = 1; o < 64; o <<= 1) {
      int u = __shfl_up(sc, o);
      if (t >= o) sc += u;
    }
    lexcl[t] = sc - v;
    int gn = b * BROWS + t;
    if (gn < N_NODES) row_ptr[gn] = es + sc - v;
  }
  if (b == NBUCK - 1 && t == 0) row_ptr[N_NODES] = ee;
  __syncthreads();
  for (int i = es + t; i < ee; i += 256) {
    uint2 v = edata[i];
    int rl = (v.x >> 16) & 63;
    int col = v.x & 0xffffu;
    float sc = ssrc[rl] + s_dst[col];
    sc = (sc > 0.f) ? sc : 0.2f * sc;                      // leaky_relu(0.2)
    float wv = __uint_as_float(v.y) / (1.f + __expf(-sc)); // sigmoid * adj
    int pos = es + lexcl[rl] + atomicAdd(&lfill[rl], 1);
    ecsr[pos] = bf16hi(wv) | (unsigned)col;
  }
}

// ------ Kernel E: agg1 edge-streaming (per-lane edata load + shfl bcast) -------
__global__ __launch_bounds__(256) void k_agg1(const unsigned* __restrict__ h1u,
    const unsigned* __restrict__ edata, const int* __restrict__ row_ptr,
    unsigned* __restrict__ h1o) {
  __shared__ int rps[NPB + 1];
  __shared__ float accs[NPB][NHID];   // 4 KB
  int t = threadIdx.x;
  int n0 = blockIdx.x * NPB;
  if (t <= NPB) rps[t] = row_ptr[min(n0 + t, N_NODES)];
  for (int i = t; i < NPB * NHID / 4; i += 256)
    ((float4*)&accs[0][0])[i] = make_float4(0.f, 0.f, 0.f, 0.f);
  __syncthreads();
  int e0 = rps[0], e1 = rps[NPB];
  int span = e1 - e0;
  int gid = t >> 5, s = t & 31;
  int chunk = (span + 7) >> 3;
  int es = e0 + gid * chunk;
  int ee = min(es + chunk, e1);
  if (es < ee) {
    int lo = 0, hi = NPB - 1;
    while (lo < hi) { int mid = (lo + hi) >> 1; if (rps[mid + 1] <= es) lo = mid + 1; else hi = mid; }
    int r = lo, nxt = rps[r + 1];
    float acc0 = 0.f, acc1 = 0.f;
    int e = es;
    while (e < ee) {
      int m = ee - e; if (m > 8) m = 8;
      unsigned ue = (s < m) ? edata[e + s] : 0u;   // one request per batch
      unsigned u[8], v[8];
#pragma unroll
      for (int i = 0; i < 8; ++i) u[i] = __shfl(ue, i, 32);
#pragma unroll
      for (int i = 0; i < 8; ++i) if (i < m) v[i] = h1u[(size_t)(u[i] & 0xffffu) * 32 + s];
#pragma unroll
      for (int i = 0; i < 8; ++i) if (i < m) {
        while (e + i >= nxt) {
          atomicAdd(&accs[r][2 * s], acc0);
          atomicAdd(&accs[r][2 * s + 1], acc1);
          acc0 = acc1 = 0.f; ++r; nxt = rps[r + 1];
        }
        float wv = hi16(u[i]);
        acc0 = fmaf(wv, lo16(v[i]), acc0);
        acc1 = fmaf(wv, hi16(v[i]), acc1);
      }
      e += m;
    }
    atomicAdd(&accs[r][2 * s], acc0);
    atomicAdd(&accs[r][2 * s + 1], acc1);
  }
  __syncthreads();
  for (int i = t; i < NPB * 32; i += 256) {
    int n = i >> 5, c = i & 31;
    int gn = n0 + n;
    if (gn < N_NODES)
      h1o[(size_t)gn * 32 + c] =
          packbf(fmaxf(accs[n][2 * c], 0.f), fmaxf(accs[n][2 * c + 1], 0.f));
  }
}

// ------ Kernel G: h2 = h1o @ W2 (bf16 in, bf16 out, stride 48 ushorts) ---------
__global__ __launch_bounds__(256) void k_h2mm(const unsigned* __restrict__ h1o,
    const float* __restrict__ W2, unsigned short* __restrict__ h2s) {
  __shared__ unsigned xs[H2ROWS * 32];  // swizzled, 8 KB
  __shared__ float W2s[NHID * NCLASS];  // 10 KB
  int t = threadIdx.x;
  int R0 = blockIdx.x * H2ROWS;
  for (int i = t; i < NHID * NCLASS; i += 256) W2s[i] = W2[i];
  for (int i = t; i < H2ROWS * 32; i += 256) {
    int r = i >> 5, ku = i & 31;
    int gr = R0 + r;
    unsigned v = (gr < N_NODES) ? h1o[(size_t)gr * 32 + ku] : 0u;
    xs[r * 32 + (ku ^ (r & 31))] = v;
  }
  __syncthreads();
  int q = t & 31, cg = t >> 5;
  int c0 = cg * 5;
  float acc[2][5] = {};
#pragma unroll 8
  for (int ku = 0; ku < 32; ++ku) {
    unsigned ua = xs[q * 32 + (ku ^ q)];
    unsigned ub = xs[(q + 32) * 32 + (ku ^ q)];
    float a0 = lo16(ua), a1 = hi16(ua);
    float b0 = lo16(ub), b1 = hi16(ub);
#pragma unroll
    for (int c = 0; c < 5; ++c) {
      float w0 = W2s[(2 * ku) * NCLASS + c0 + c];
      float w1 = W2s[(2 * ku + 1) * NCLASS + c0 + c];
      acc[0][c] = fmaf(a0, w0, acc[0][c]);
      acc[0][c] = fmaf(a1, w1, acc[0][c]);
      acc[1][c] = fmaf(b0, w0, acc[1][c]);
      acc[1][c] = fmaf(b1, w1, acc[1][c]);
    }
  }
#pragma unroll
  for (int j = 0; j < 2; ++j) {
    int gr = R0 + q + j * 32;
    if (gr < N_NODES) {
#pragma unroll
      for (int c = 0; c < 5; ++c)
        h2s[(size_t)gr * H2STRIDE + c0 + c] = (unsigned short)(bf16hi(acc[j][c]) >> 16);
    }
  }
}

// ------ Kernel F: agg2 edge-streaming (per-lane load + shfl) + res + LN --------
__global__ __launch_bounds__(256) void k_agg2(const unsigned short* __restrict__ h2s,
    const unsigned* __restrict__ edata, const int* __restrict__ row_ptr,
    const float* __restrict__ res, const float* __restrict__ ln_g,
    const float* __restrict__ ln_b, float* __restrict__ out) {
  __shared__ int rps[NPB + 1];
  __shared__ float accs[NPB][NCLASS];   // 2.5 KB
  int t = threadIdx.x;
  int n0 = blockIdx.x * NPB;
  if (t <= NPB) rps[t] = row_ptr[min(n0 + t, N_NODES)];
  for (int i = t; i < NPB * NCLASS; i += 256) ((float*)accs)[i] = 0.f;
  __syncthreads();
  int e0 = rps[0], e1 = rps[NPB];
  int span = e1 - e0;
  int gid = t >> 5, s = t & 31;
  int chunk = (span + 7) >> 3;
  int es = e0 + gid * chunk;
  int ee = min(es + chunk, e1);
  bool act = (s < 20);
  if (es < ee) {
    int lo = 0, hi = NPB - 1;
    while (lo < hi) { int mid = (lo + hi) >> 1; if (rps[mid + 1] <= es) lo = mid + 1; else hi = mid; }
    int r = lo, nxt = rps[r + 1];
    float acc0 = 0.f, acc1 = 0.f;
    int e = es;
    while (e < ee) {
      int m = ee - e; if (m > 8) m = 8;
      unsigned ue = (s < m) ? edata[e + s] : 0u;   // one request per batch
      unsigned u[8], v[8];
#pragma unroll
      for (int i = 0; i < 8; ++i) u[i] = __shfl(ue, i, 32);
#pragma unroll
      for (int i = 0; i < 8; ++i) {
        v[i] = 0u;
        if (i < m && act)
          v[i] = *(const unsigned*)(h2s + (size_t)(u[i] & 0xffffu) * H2STRIDE + 2 * s);
      }
#pragma unroll
      for (int i = 0; i < 8; ++i) if (i < m) {
        while (e + i >= nxt) {
          if (act) {
            atomicAdd(&accs[r][2 * s], acc0);
            atomicAdd(&accs[r][2 * s + 1], acc1);
          }
          acc0 = acc1 = 0.f; ++r; nxt = rps[r + 1];
        }
        float wv = hi16(u[i]);
        acc0 = fmaf(wv, lo16(v[i]), acc0);
        acc1 = fmaf(wv, hi16(v[i]), acc1);
      }
      e += m;
    }
    if (act) {
      atomicAdd(&accs[r][2 * s], acc0);
      atomicAdd(&accs[r][2 * s + 1], acc1);
    }
  }
  __syncthreads();
  int wave = t >> 6, lane = t & 63;
  for (int k = 0; k < NPB / 4; ++k) {
    int n = wave * (NPB / 4) + k;
    int gn = n0 + n;
    if (gn >= N_NODES) break;
    float y = 0.f;
    if (lane < NCLASS)
      y = fmaxf(accs[n][lane], 0.f) + res[(size_t)gn * NCLASS + lane];
    float s1 = y, s2 = y * y;
#pragma unroll
    for (int off = 1; off < 64; off <<= 1) {
      s1 += __shfl_xor(s1, off);
      s2 += __shfl_xor(s2, off);
    }
    float mu = s1 / (float)NCLASS;
    float var = s2 / (float)NCLASS - mu * mu;
    float inv = rsqrtf(var + LN_EPS);
    if (lane < NCLASS)
      out[(size_t)gn * NCLASS + lane] = (y - mu) * inv * ln_g[lane] + ln_b[lane];
  }
}

// -------------------------------------------------------------------------------
extern "C" void kernel_launch(void* const* d_in, const int* in_sizes, int n_in,
                              void* d_out, int out_size, void* d_ws, size_t ws_size,
                              hipStream_t stream) {
  const float* x     = (const float*)d_in[0];
  const int*   ei    = (const int*)  d_in[1];
  const float* adj   = (const float*)d_in[2];
  const float* W1    = (const float*)d_in[3];
  const float* a1    = (const float*)d_in[4];
  const float* W2    = (const float*)d_in[5];
  const float* res_w = (const float*)d_in[6];
  const float* res_b = (const float*)d_in[7];
  const float* ln_g  = (const float*)d_in[8];
  const float* ln_b  = (const float*)d_in[9];
  float* out = (float*)d_out;

  char* ws = (char*)d_ws;
  size_t off = 0;
  auto alloc = [&](size_t bytes) -> void* {
    void* p = (void*)(ws + off);
    off += (bytes + 255) & ~(size_t)255;
    return p;
  };

  unsigned*       h1u     = (unsigned*)alloc((size_t)N_NODES * 32 * 4);  // bf16x2
  float*          s_src   = (float*)alloc((size_t)N_NODES * 4);
  float*          s_dst   = (float*)alloc((size_t)N_NODES * 4);
  int*            bcnt    = (int*)alloc((size_t)NBUCK * 4);
  int*            gptr    = (int*)alloc((size_t)(NBUCK + 1) * 4);
  int*            ccnt    = (int*)alloc((size_t)NCHUNK * NBUCK * 4);
  int*            cbase   = (int*)alloc((size_t)NCHUNK * NBUCK * 4);
  int*            row_ptr = (int*)alloc((size_t)(N_NODES + 1) * 4);
  uint2*          edata   = (uint2*)alloc((size_t)N_EDGES * 8);
  unsigned*       ecsr    = (unsigned*)alloc((size_t)N_EDGES * 4);
  unsigned*       h1o     = (unsigned*)alloc((size_t)N_NODES * 32 * 4);  // bf16x2
  unsigned short* h2s     = (unsigned short*)alloc((size_t)N_NODES * H2STRIDE * 2);
  float*          res     = (float*)alloc((size_t)N_NODES * NCLASS * 4);
  (void)ws_size; (void)in_sizes; (void)n_in; (void)out_size;

  const int NBLK_H1  = (N_NODES + 63) / 64;              // 782
  const int NBLK_RES = (N_NODES + 127) / 128;            // 391
  const int NBLK_H2  = (N_NODES + H2ROWS - 1) / H2ROWS;  // 782
  const int NBLK_AGG = (N_NODES + NPB - 1) / NPB;        // 3125

  k_h1mm<<<NBLK_H1, 256, 0, stream>>>(x, W1, a1, h1u, s_src, s_dst, bcnt);
  k_resmm<<<NBLK_RES, 256, 0, stream>>>(x, res_w, res_b, res, ei, bcnt, ccnt, cbase);
  k_bscan<<<1, 256, 0, stream>>>(bcnt, gptr);
  k_bscatter<<<NCHUNK, 256, 0, stream>>>(ei, adj, gptr, ccnt, cbase, edata);
  k_csr<<<NBUCK, 256, 0, stream>>>(edata, gptr, s_src, s_dst, row_ptr, ecsr);
  k_agg1<<<NBLK_AGG, 256, 0, stream>>>(h1u, ecsr, row_ptr, h1o);
  k_h2mm<<<NBLK_H2, 256, 0, stream>>>(h1o, W2, h2s);
  k_agg2<<<NBLK_AGG, 256, 0, stream>>>(h2s, ecsr, row_ptr, res, ln_g, ln_b, out);
}

// Round 18
// 162.817 us; speedup vs baseline: 1.2627x; 1.1145x over previous
//
#include <hip/hip_runtime.h>
#include <math.h>

#define N_NODES 50000
#define N_EDGES 800000
#define NFEAT 128
#define NHID 64
#define NCLASS 40
#define LN_EPS 1e-5f
#define BROWS 64                                // rows per bucket
#define NBUCK ((N_NODES + BROWS - 1) / BROWS)   // 782
#define CHUNK 4096                              // edges per chunk
#define NCHUNK ((N_EDGES + CHUNK - 1) / CHUNK)  // 196
#define NPB 16                                  // nodes per agg block
#define H2ROWS 64
#define H2STRIDE 48                             // ushorts/row (96B, <=2 lines)

__device__ __forceinline__ int swz(int k) { return ((k >> 2) & 7) << 2; }

__device__ __forceinline__ unsigned packbf(float a, float b) {
  unsigned ua = __float_as_uint(a), ub = __float_as_uint(b);
  ua += 0x7fffu + ((ua >> 16) & 1u);
  ub += 0x7fffu + ((ub >> 16) & 1u);
  return (ua >> 16) | (ub & 0xffff0000u);
}
__device__ __forceinline__ unsigned bf16hi(float a) {
  unsigned u = __float_as_uint(a);
  u += 0x7fffu + ((u >> 16) & 1u);
  return u & 0xffff0000u;
}
__device__ __forceinline__ float lo16(unsigned v) { return __uint_as_float(v << 16); }
__device__ __forceinline__ float hi16(unsigned v) { return __uint_as_float(v & 0xffff0000u); }

// ------ Kernel A: h1 = x @ W1 (reg-blocked 4x4) + fused s_src/s_dst ------------
// block 0 also zeroes bcnt (stream order: completes before k_resmm's histogram)
__global__ __launch_bounds__(256) void k_h1mm(const float* __restrict__ x,
    const float* __restrict__ W1, const float* __restrict__ a1,
    unsigned* __restrict__ h1u, float* __restrict__ s_src, float* __restrict__ s_dst,
    int* __restrict__ bcnt) {
  __shared__ float xT[NFEAT * 64];    // 32 KB
  __shared__ float W1s[NFEAT * NHID]; // 32 KB
  int t = threadIdx.x;
  if (blockIdx.x == 0)
    for (int i = t; i < NBUCK; i += 256) bcnt[i] = 0;
  int R0 = blockIdx.x * 64;
  for (int i = t; i < NFEAT * NHID / 4; i += 256)
    ((float4*)W1s)[i] = ((const float4*)W1)[i];
#pragma unroll
  for (int it = 0; it < 8; ++it) {
    int i = t + it * 256;
    int r = i >> 5, kq = i & 31;
    int gr = R0 + r;
    float4 v = make_float4(0.f, 0.f, 0.f, 0.f);
    if (gr < N_NODES) v = *(const float4*)(x + (size_t)gr * NFEAT + kq * 4);
    int rw = r ^ ((kq & 7) << 2);
    xT[(kq * 4 + 0) * 64 + rw] = v.x;
    xT[(kq * 4 + 1) * 64 + rw] = v.y;
    xT[(kq * 4 + 2) * 64 + rw] = v.z;
    xT[(kq * 4 + 3) * 64 + rw] = v.w;
  }
  __syncthreads();
  int cg = t & 15, rg = t >> 4;
  int c0 = cg * 4, r0 = rg * 4;
  float acc[4][4] = {};
#pragma unroll 4
  for (int k = 0; k < NFEAT; ++k) {
    float4 xv = *(const float4*)&xT[k * 64 + (r0 ^ swz(k))];
    float4 wv = *(const float4*)&W1s[k * NHID + c0];
    float xr[4] = {xv.x, xv.y, xv.z, xv.w};
    float wr[4] = {wv.x, wv.y, wv.z, wv.w};
#pragma unroll
    for (int j = 0; j < 4; ++j)
#pragma unroll
      for (int c = 0; c < 4; ++c)
        acc[j][c] = fmaf(xr[j], wr[c], acc[j][c]);
  }
  float4 as = *(const float4*)(a1 + c0);
  float4 ad = *(const float4*)(a1 + NHID + c0);
  float asr[4] = {as.x, as.y, as.z, as.w};
  float adr[4] = {ad.x, ad.y, ad.z, ad.w};
  float ps[4], pd[4];
#pragma unroll
  for (int j = 0; j < 4; ++j) {
    int gr = R0 + r0 + j;
    if (gr < N_NODES) {
      uint2 pk;
      pk.x = packbf(acc[j][0], acc[j][1]);
      pk.y = packbf(acc[j][2], acc[j][3]);
      *(uint2*)&h1u[(size_t)gr * 32 + (c0 >> 1)] = pk;
    }
    float s = 0.f, d = 0.f;
#pragma unroll
    for (int c = 0; c < 4; ++c) {
      s = fmaf(acc[j][c], asr[c], s);
      d = fmaf(acc[j][c], adr[c], d);
    }
    ps[j] = s; pd[j] = d;
  }
#pragma unroll
  for (int j = 0; j < 4; ++j)
#pragma unroll
    for (int off = 1; off < 16; off <<= 1) {
      ps[j] += __shfl_xor(ps[j], off);
      pd[j] += __shfl_xor(pd[j], off);
    }
  if (cg == 0) {
#pragma unroll
    for (int j = 0; j < 4; ++j) {
      int gr = R0 + r0 + j;
      if (gr < N_NODES) { s_src[gr] = ps[j]; s_dst[gr] = pd[j]; }
    }
  }
}

// ------ Kernel R: res = x @ res_w^T + res_b (64-row tile, 2x5/thread) ----------
// + fused bucket histogram with per-chunk counts & global reservations
__global__ __launch_bounds__(256) void k_resmm(const float* __restrict__ x,
    const float* __restrict__ res_w, const float* __restrict__ res_b,
    float* __restrict__ res, const int* __restrict__ ei, int* __restrict__ bcnt,
    int* __restrict__ ccnt, int* __restrict__ cbase) {
  __shared__ float xT[NFEAT * 64];      // 32 KB
  __shared__ float rwT[NFEAT * NCLASS]; // 20 KB
  int t = threadIdx.x;
  int R0 = blockIdx.x * 64;
  for (int i = t; i < NCLASS * NFEAT; i += 256) {
    int c = i / NFEAT, k = i % NFEAT;
    rwT[k * NCLASS + c] = res_w[i];
  }
#pragma unroll
  for (int it = 0; it < 8; ++it) {
    int i = t + it * 256;
    int r = i >> 5, kq = i & 31;
    int gr = R0 + r;
    float4 v = make_float4(0.f, 0.f, 0.f, 0.f);
    if (gr < N_NODES) v = *(const float4*)(x + (size_t)gr * NFEAT + kq * 4);
    int rw = r ^ ((kq & 7) << 2);
    xT[(kq * 4 + 0) * 64 + rw] = v.x;
    xT[(kq * 4 + 1) * 64 + rw] = v.y;
    xT[(kq * 4 + 2) * 64 + rw] = v.z;
    xT[(kq * 4 + 3) * 64 + rw] = v.w;
  }
  __syncthreads();
  int cg = t & 7, rg = t >> 3;           // 8 col-groups x 32 row-groups
  int c0 = cg * 5, r0 = rg * 2;
  float acc[2][5] = {};
#pragma unroll 4
  for (int k = 0; k < NFEAT; ++k) {
    float2 xv = *(const float2*)&xT[k * 64 + (r0 ^ swz(k))];
    float xr[2] = {xv.x, xv.y};
    float wr[5];
#pragma unroll
    for (int c = 0; c < 5; ++c) wr[c] = rwT[k * NCLASS + c0 + c];
#pragma unroll
    for (int j = 0; j < 2; ++j)
#pragma unroll
      for (int c = 0; c < 5; ++c)
        acc[j][c] = fmaf(xr[j], wr[c], acc[j][c]);
  }
  float bb[5];
#pragma unroll
  for (int c = 0; c < 5; ++c) bb[c] = res_b[c0 + c];
#pragma unroll
  for (int j = 0; j < 2; ++j) {
    int gr = R0 + r0 + j;
    if (gr < N_NODES) {
#pragma unroll
      for (int c = 0; c < 5; ++c)
        res[(size_t)gr * NCLASS + c0 + c] = acc[j][c] + bb[c];
    }
  }
  // ---- fused bucket histogram: per-chunk counts + global reservation ----------
  if (blockIdx.x < NCHUNK) {
    __syncthreads();
    int* cnt = (int*)xT;
    for (int i = t; i < NBUCK; i += 256) cnt[i] = 0;
    __syncthreads();
    int e0 = blockIdx.x * CHUNK;
    int ecnt = min(CHUNK, N_EDGES - e0);
    for (int i = t; i < ecnt; i += 256)
      atomicAdd(&cnt[ei[e0 + i] >> 6], 1);
    __syncthreads();
    for (int i = t; i < NBUCK; i += 256) {
      int c = cnt[i];
      int base = (c > 0) ? atomicAdd(&bcnt[i], c) : 0;
      ccnt[blockIdx.x * NBUCK + i] = c;
      cbase[blockIdx.x * NBUCK + i] = base;
    }
  }
}

// ------ Kernel C: scan buckets -> gptr -----------------------------------------
__global__ __launch_bounds__(256) void k_bscan(const int* __restrict__ bcnt,
    int* __restrict__ gptr) {
  __shared__ int psum[256];
  int t = threadIdx.x;
  int base = t * 4;
  int s[4];
#pragma unroll
  for (int j = 0; j < 4; ++j)
    s[j] = (base + j < NBUCK) ? bcnt[base + j] : 0;
  int local = s[0] + s[1] + s[2] + s[3];
  psum[t] = local;
  __syncthreads();
#pragma unroll
  for (int o = 1; o < 256; o <<= 1) {
    int v = (t >= o) ? psum[t - o] : 0;
    __syncthreads();
    psum[t] += v;
    __syncthreads();
  }
  int excl = psum[t] - local;
#pragma unroll
  for (int j = 0; j < 4; ++j) {
    if (base + j < NBUCK) gptr[base + j] = excl;
    excl += s[j];
  }
  if (t == 255) gptr[NBUCK] = psum[255];
}

// ------ Kernel D: bucket scatter, single edge pass (bases precomputed) ---------
__global__ __launch_bounds__(256) void k_bscatter(const int* __restrict__ ei,
    const float* __restrict__ adj, const int* __restrict__ gptr,
    const int* __restrict__ ccnt, const int* __restrict__ cbase,
    uint2* __restrict__ edata) {
  __shared__ int cnt[NBUCK];
  __shared__ int off[NBUCK];
  __shared__ int gbase[NBUCK];
  __shared__ int po[NBUCK];
  __shared__ int psum[256];
  __shared__ uint2 stage[CHUNK];   // 32 KB
  int t = threadIdx.x;
  int cix = blockIdx.x;
  int e0 = cix * CHUNK;
  int ecnt = min(CHUNK, N_EDGES - e0);
  for (int i = t; i < NBUCK; i += 256) {
    int c = ccnt[cix * NBUCK + i];
    cnt[i] = c;
    gbase[i] = gptr[i] + cbase[cix * NBUCK + i];
    po[i] = 0;
  }
  __syncthreads();
  int base = t * 4;
  int s0 = (base < NBUCK) ? cnt[base] : 0;
  int s1 = (base + 1 < NBUCK) ? cnt[base + 1] : 0;
  int s2 = (base + 2 < NBUCK) ? cnt[base + 2] : 0;
  int s3 = (base + 3 < NBUCK) ? cnt[base + 3] : 0;
  int local = s0 + s1 + s2 + s3;
  psum[t] = local;
  __syncthreads();
#pragma unroll
  for (int o = 1; o < 256; o <<= 1) {
    int v = (t >= o) ? psum[t - o] : 0;
    __syncthreads();
    psum[t] += v;
    __syncthreads();
  }
  int excl = psum[t] - local;
  if (base < NBUCK)     off[base]     = excl;
  if (base + 1 < NBUCK) off[base + 1] = excl + s0;
  if (base + 2 < NBUCK) off[base + 2] = excl + s0 + s1;
  if (base + 3 < NBUCK) off[base + 3] = excl + s0 + s1 + s2;
  __syncthreads();
  for (int i = t; i < ecnt; i += 256) {
    int e = e0 + i;
    int row = ei[e], col = ei[N_EDGES + e];
    int b = row >> 6;
    int pos = off[b] + atomicAdd(&po[b], 1);
    stage[pos] = make_uint2(((unsigned)b << 22) | ((unsigned)(row & 63) << 16) |
                            (unsigned)col, __float_as_uint(adj[e]));
  }
  __syncthreads();
  for (int i = t; i < ecnt; i += 256) {
    uint2 v = stage[i];
    int b = v.x >> 22;
    edata[(size_t)gbase[b] + (i - off[b])] = v;
  }
}

// ------ Kernel S: per-bucket CSR + edge weights (s_src via LDS) ----------------
__global__ __launch_bounds__(256) void k_csr(const uint2* __restrict__ edata,
    const int* __restrict__ gptr, const float* __restrict__ s_src,
    const float* __restrict__ s_dst, int* __restrict__ row_ptr,
    unsigned* __restrict__ ecsr) {
  __shared__ int lcnt[BROWS];
  __shared__ int lexcl[BROWS];
  __shared__ int lfill[BROWS];
  __shared__ float ssrc[BROWS];
  int t = threadIdx.x;
  int b = blockIdx.x;
  int es = gptr[b], ee = gptr[b + 1];
  if (t < BROWS) {
    lcnt[t] = 0; lfill[t] = 0;
    int gn = b * BROWS + t;
    ssrc[t] = (gn < N_NODES) ? s_src[gn] : 0.f;
  }
  __syncthreads();
  for (int i = es + t; i < ee; i += 256)
    atomicAdd(&lcnt[(edata[i].x >> 16) & 63u], 1);
  __syncthreads();
  if (t < 64) {  // wave 0: 64-lane inclusive scan
    int v = lcnt[t];
    int sc = v;
#pragma unroll
    for (int o = 1; o < 64; o <<= 1) {
      int u = __shfl_up(sc, o);
      if (t >= o) sc += u;
    }
    lexcl[t] = sc - v;
    int gn = b * BROWS + t;
    if (gn < N_NODES) row_ptr[gn] = es + sc - v;
  }
  if (b == NBUCK - 1 && t == 0) row_ptr[N_NODES] = ee;
  __syncthreads();
  for (int i = es + t; i < ee; i += 256) {
    uint2 v = edata[i];
    int rl = (v.x >> 16) & 63;
    int col = v.x & 0xffffu;
    float sc = ssrc[rl] + s_dst[col];
    sc = (sc > 0.f) ? sc : 0.2f * sc;                      // leaky_relu(0.2)
    float wv = __uint_as_float(v.y) / (1.f + __expf(-sc)); // sigmoid * adj
    int pos = es + lexcl[rl] + atomicAdd(&lfill[rl], 1);
    ecsr[pos] = bf16hi(wv) | (unsigned)col;
  }
}

// ------ Kernel E: agg1 edge-streaming (per-lane edata load + shfl bcast) -------
__global__ __launch_bounds__(256) void k_agg1(const unsigned* __restrict__ h1u,
    const unsigned* __restrict__ edata, const int* __restrict__ row_ptr,
    unsigned* __restrict__ h1o) {
  __shared__ int rps[NPB + 1];
  __shared__ float accs[NPB][NHID];   // 4 KB
  int t = threadIdx.x;
  int n0 = blockIdx.x * NPB;
  if (t <= NPB) rps[t] = row_ptr[min(n0 + t, N_NODES)];
  for (int i = t; i < NPB * NHID / 4; i += 256)
    ((float4*)&accs[0][0])[i] = make_float4(0.f, 0.f, 0.f, 0.f);
  __syncthreads();
  int e0 = rps[0], e1 = rps[NPB];
  int span = e1 - e0;
  int gid = t >> 5, s = t & 31;
  int chunk = (span + 7) >> 3;
  int es = e0 + gid * chunk;
  int ee = min(es + chunk, e1);
  if (es < ee) {
    int lo = 0, hi = NPB - 1;
    while (lo < hi) { int mid = (lo + hi) >> 1; if (rps[mid + 1] <= es) lo = mid + 1; else hi = mid; }
    int r = lo, nxt = rps[r + 1];
    float acc0 = 0.f, acc1 = 0.f;
    int e = es;
    while (e < ee) {
      int m = ee - e; if (m > 8) m = 8;
      unsigned ue = (s < m) ? edata[e + s] : 0u;   // one request per batch
      unsigned u[8], v[8];
#pragma unroll
      for (int i = 0; i < 8; ++i) u[i] = __shfl(ue, i, 32);
#pragma unroll
      for (int i = 0; i < 8; ++i) if (i < m) v[i] = h1u[(size_t)(u[i] & 0xffffu) * 32 + s];
#pragma unroll
      for (int i = 0; i < 8; ++i) if (i < m) {
        while (e + i >= nxt) {
          atomicAdd(&accs[r][2 * s], acc0);
          atomicAdd(&accs[r][2 * s + 1], acc1);
          acc0 = acc1 = 0.f; ++r; nxt = rps[r + 1];
        }
        float wv = hi16(u[i]);
        acc0 = fmaf(wv, lo16(v[i]), acc0);
        acc1 = fmaf(wv, hi16(v[i]), acc1);
      }
      e += m;
    }
    atomicAdd(&accs[r][2 * s], acc0);
    atomicAdd(&accs[r][2 * s + 1], acc1);
  }
  __syncthreads();
  for (int i = t; i < NPB * 32; i += 256) {
    int n = i >> 5, c = i & 31;
    int gn = n0 + n;
    if (gn < N_NODES)
      h1o[(size_t)gn * 32 + c] =
          packbf(fmaxf(accs[n][2 * c], 0.f), fmaxf(accs[n][2 * c + 1], 0.f));
  }
}

// ------ Kernel G: h2 = h1o @ W2 (bf16 in, bf16 out, stride 48 ushorts) ---------
__global__ __launch_bounds__(256) void k_h2mm(const unsigned* __restrict__ h1o,
    const float* __restrict__ W2, unsigned short* __restrict__ h2s) {
  __shared__ unsigned xs[H2ROWS * 32];  // swizzled, 8 KB
  __shared__ float W2s[NHID * NCLASS];  // 10 KB
  int t = threadIdx.x;
  int R0 = blockIdx.x * H2ROWS;
  for (int i = t; i < NHID * NCLASS; i += 256) W2s[i] = W2[i];
  for (int i = t; i < H2ROWS * 32; i += 256) {
    int r = i >> 5, ku = i & 31;
    int gr = R0 + r;
    unsigned v = (gr < N_NODES) ? h1o[(size_t)gr * 32 + ku] : 0u;
    xs[r * 32 + (ku ^ (r & 31))] = v;
  }
  __syncthreads();
  int q = t & 31, cg = t >> 5;
  int c0 = cg * 5;
  float acc[2][5] = {};
#pragma unroll 8
  for (int ku = 0; ku < 32; ++ku) {
    unsigned ua = xs[q * 32 + (ku ^ q)];
    unsigned ub = xs[(q + 32) * 32 + (ku ^ q)];
    float a0 = lo16(ua), a1 = hi16(ua);
    float b0 = lo16(ub), b1 = hi16(ub);
#pragma unroll
    for (int c = 0; c < 5; ++c) {
      float w0 = W2s[(2 * ku) * NCLASS + c0 + c];
      float w1 = W2s[(2 * ku + 1) * NCLASS + c0 + c];
      acc[0][c] = fmaf(a0, w0, acc[0][c]);
      acc[0][c] = fmaf(a1, w1, acc[0][c]);
      acc[1][c] = fmaf(b0, w0, acc[1][c]);
      acc[1][c] = fmaf(b1, w1, acc[1][c]);
    }
  }
#pragma unroll
  for (int j = 0; j < 2; ++j) {
    int gr = R0 + q + j * 32;
    if (gr < N_NODES) {
#pragma unroll
      for (int c = 0; c < 5; ++c)
        h2s[(size_t)gr * H2STRIDE + c0 + c] = (unsigned short)(bf16hi(acc[j][c]) >> 16);
    }
  }
}

// ------ Kernel F: agg2 edge-streaming (per-lane load + shfl) + res + LN --------
__global__ __launch_bounds__(256) void k_agg2(const unsigned short* __restrict__ h2s,
    const unsigned* __restrict__ edata, const int* __restrict__ row_ptr,
    const float* __restrict__ res, const float* __restrict__ ln_g,
    const float* __restrict__ ln_b, float* __restrict__ out) {
  __shared__ int rps[NPB + 1];
  __shared__ float accs[NPB][NCLASS];   // 2.5 KB
  int t = threadIdx.x;
  int n0 = blockIdx.x * NPB;
  if (t <= NPB) rps[t] = row_ptr[min(n0 + t, N_NODES)];
  for (int i = t; i < NPB * NCLASS; i += 256) ((float*)accs)[i] = 0.f;
  __syncthreads();
  int e0 = rps[0], e1 = rps[NPB];
  int span = e1 - e0;
  int gid = t >> 5, s = t & 31;
  int chunk = (span + 7) >> 3;
  int es = e0 + gid * chunk;
  int ee = min(es + chunk, e1);
  bool act = (s < 20);
  if (es < ee) {
    int lo = 0, hi = NPB - 1;
    while (lo < hi) { int mid = (lo + hi) >> 1; if (rps[mid + 1] <= es) lo = mid + 1; else hi = mid; }
    int r = lo, nxt = rps[r + 1];
    float acc0 = 0.f, acc1 = 0.f;
    int e = es;
    while (e < ee) {
      int m = ee - e; if (m > 8) m = 8;
      unsigned ue = (s < m) ? edata[e + s] : 0u;   // one request per batch
      unsigned u[8], v[8];
#pragma unroll
      for (int i = 0; i < 8; ++i) u[i] = __shfl(ue, i, 32);
#pragma unroll
      for (int i = 0; i < 8; ++i) {
        v[i] = 0u;
        if (i < m && act)
          v[i] = *(const unsigned*)(h2s + (size_t)(u[i] & 0xffffu) * H2STRIDE + 2 * s);
      }
#pragma unroll
      for (int i = 0; i < 8; ++i) if (i < m) {
        while (e + i >= nxt) {
          if (act) {
            atomicAdd(&accs[r][2 * s], acc0);
            atomicAdd(&accs[r][2 * s + 1], acc1);
          }
          acc0 = acc1 = 0.f; ++r; nxt = rps[r + 1];
        }
        float wv = hi16(u[i]);
        acc0 = fmaf(wv, lo16(v[i]), acc0);
        acc1 = fmaf(wv, hi16(v[i]), acc1);
      }
      e += m;
    }
    if (act) {
      atomicAdd(&accs[r][2 * s], acc0);
      atomicAdd(&accs[r][2 * s + 1], acc1);
    }
  }
  __syncthreads();
  int wave = t >> 6, lane = t & 63;
  for (int k = 0; k < NPB / 4; ++k) {
    int n = wave * (NPB / 4) + k;
    int gn = n0 + n;
    if (gn >= N_NODES) break;
    float y = 0.f;
    if (lane < NCLASS)
      y = fmaxf(accs[n][lane], 0.f) + res[(size_t)gn * NCLASS + lane];
    float s1 = y, s2 = y * y;
#pragma unroll
    for (int off = 1; off < 64; off <<= 1) {
      s1 += __shfl_xor(s1, off);
      s2 += __shfl_xor(s2, off);
    }
    float mu = s1 / (float)NCLASS;
    float var = s2 / (float)NCLASS - mu * mu;
    float inv = rsqrtf(var + LN_EPS);
    if (lane < NCLASS)
      out[(size_t)gn * NCLASS + lane] = (y - mu) * inv * ln_g[lane] + ln_b[lane];
  }
}

// -------------------------------------------------------------------------------
extern "C" void kernel_launch(void* const* d_in, const int* in_sizes, int n_in,
                              void* d_out, int out_size, void* d_ws, size_t ws_size,
                              hipStream_t stream) {
  const float* x     = (const float*)d_in[0];
  const int*   ei    = (const int*)  d_in[1];
  const float* adj   = (const float*)d_in[2];
  const float* W1    = (const float*)d_in[3];
  const float* a1    = (const float*)d_in[4];
  const float* W2    = (const float*)d_in[5];
  const float* res_w = (const float*)d_in[6];
  const float* res_b = (const float*)d_in[7];
  const float* ln_g  = (const float*)d_in[8];
  const float* ln_b  = (const float*)d_in[9];
  float* out = (float*)d_out;

  char* ws = (char*)d_ws;
  size_t off = 0;
  auto alloc = [&](size_t bytes) -> void* {
    void* p = (void*)(ws + off);
    off += (bytes + 255) & ~(size_t)255;
    return p;
  };

  unsigned*       h1u     = (unsigned*)alloc((size_t)N_NODES * 32 * 4);  // bf16x2
  float*          s_src   = (float*)alloc((size_t)N_NODES * 4);
  float*          s_dst   = (float*)alloc((size_t)N_NODES * 4);
  int*            bcnt    = (int*)alloc((size_t)NBUCK * 4);
  int*            gptr    = (int*)alloc((size_t)(NBUCK + 1) * 4);
  int*            ccnt    = (int*)alloc((size_t)NCHUNK * NBUCK * 4);
  int*            cbase   = (int*)alloc((size_t)NCHUNK * NBUCK * 4);
  int*            row_ptr = (int*)alloc((size_t)(N_NODES + 1) * 4);
  uint2*          edata   = (uint2*)alloc((size_t)N_EDGES * 8);
  unsigned*       ecsr    = (unsigned*)alloc((size_t)N_EDGES * 4);
  unsigned*       h1o     = (unsigned*)alloc((size_t)N_NODES * 32 * 4);  // bf16x2
  unsigned short* h2s     = (unsigned short*)alloc((size_t)N_NODES * H2STRIDE * 2);
  float*          res     = (float*)alloc((size_t)N_NODES * NCLASS * 4);
  (void)ws_size; (void)in_sizes; (void)n_in; (void)out_size;

  const int NBLK_H1  = (N_NODES + 63) / 64;              // 782
  const int NBLK_RES = (N_NODES + 63) / 64;              // 782
  const int NBLK_H2  = (N_NODES + H2ROWS - 1) / H2ROWS;  // 782
  const int NBLK_AGG = (N_NODES + NPB - 1) / NPB;        // 3125

  k_h1mm<<<NBLK_H1, 256, 0, stream>>>(x, W1, a1, h1u, s_src, s_dst, bcnt);
  k_resmm<<<NBLK_RES, 256, 0, stream>>>(x, res_w, res_b, res, ei, bcnt, ccnt, cbase);
  k_bscan<<<1, 256, 0, stream>>>(bcnt, gptr);
  k_bscatter<<<NCHUNK, 256, 0, stream>>>(ei, adj, gptr, ccnt, cbase, edata);
  k_csr<<<NBUCK, 256, 0, stream>>>(edata, gptr, s_src, s_dst, row_ptr, ecsr);
  k_agg1<<<NBLK_AGG, 256, 0, stream>>>(h1u, ecsr, row_ptr, h1o);
  k_h2mm<<<NBLK_H2, 256, 0, stream>>>(h1o, W2, h2s);
  k_agg2<<<NBLK_AGG, 256, 0, stream>>>(h2s, ecsr, row_ptr, res, ln_g, ln_b, out);
}

// Round 19
// 160.840 us; speedup vs baseline: 1.2782x; 1.0123x over previous
//
#include <hip/hip_runtime.h>
#include <math.h>

#define N_NODES 50000
#define N_EDGES 800000
#define NFEAT 128
#define NHID 64
#define NCLASS 40
#define LN_EPS 1e-5f
#define BROWS 64                                // rows per bucket
#define NBUCK ((N_NODES + BROWS - 1) / BROWS)   // 782
#define CHUNK 4096                              // edges per chunk
#define NCHUNK ((N_EDGES + CHUNK - 1) / CHUNK)  // 196
#define NPB 16                                  // nodes per agg block
#define H2ROWS 64
#define H2STRIDE 48                             // ushorts/row (96B, <=2 lines)

__device__ __forceinline__ int swz(int k) { return ((k >> 2) & 7) << 2; }

__device__ __forceinline__ unsigned packbf(float a, float b) {
  unsigned ua = __float_as_uint(a), ub = __float_as_uint(b);
  ua += 0x7fffu + ((ua >> 16) & 1u);
  ub += 0x7fffu + ((ub >> 16) & 1u);
  return (ua >> 16) | (ub & 0xffff0000u);
}
__device__ __forceinline__ unsigned bf16hi(float a) {
  unsigned u = __float_as_uint(a);
  u += 0x7fffu + ((u >> 16) & 1u);
  return u & 0xffff0000u;
}
__device__ __forceinline__ float lo16(unsigned v) { return __uint_as_float(v << 16); }
__device__ __forceinline__ float hi16(unsigned v) { return __uint_as_float(v & 0xffff0000u); }

// ------ Kernel A: h1 = x @ W1 (reg-blocked 4x4) + fused s_src/s_dst ------------
// block 0 also zeroes bcnt (stream order: completes before k_resmm's histogram)
__global__ __launch_bounds__(256) void k_h1mm(const float* __restrict__ x,
    const float* __restrict__ W1, const float* __restrict__ a1,
    unsigned* __restrict__ h1u, float* __restrict__ s_src, float* __restrict__ s_dst,
    int* __restrict__ bcnt) {
  __shared__ float xT[NFEAT * 64];    // 32 KB
  __shared__ float W1s[NFEAT * NHID]; // 32 KB
  int t = threadIdx.x;
  if (blockIdx.x == 0)
    for (int i = t; i < NBUCK; i += 256) bcnt[i] = 0;
  int R0 = blockIdx.x * 64;
  for (int i = t; i < NFEAT * NHID / 4; i += 256)
    ((float4*)W1s)[i] = ((const float4*)W1)[i];
#pragma unroll
  for (int it = 0; it < 8; ++it) {
    int i = t + it * 256;
    int r = i >> 5, kq = i & 31;
    int gr = R0 + r;
    float4 v = make_float4(0.f, 0.f, 0.f, 0.f);
    if (gr < N_NODES) v = *(const float4*)(x + (size_t)gr * NFEAT + kq * 4);
    int rw = r ^ ((kq & 7) << 2);
    xT[(kq * 4 + 0) * 64 + rw] = v.x;
    xT[(kq * 4 + 1) * 64 + rw] = v.y;
    xT[(kq * 4 + 2) * 64 + rw] = v.z;
    xT[(kq * 4 + 3) * 64 + rw] = v.w;
  }
  __syncthreads();
  int cg = t & 15, rg = t >> 4;
  int c0 = cg * 4, r0 = rg * 4;
  float acc[4][4] = {};
#pragma unroll 4
  for (int k = 0; k < NFEAT; ++k) {
    float4 xv = *(const float4*)&xT[k * 64 + (r0 ^ swz(k))];
    float4 wv = *(const float4*)&W1s[k * NHID + c0];
    float xr[4] = {xv.x, xv.y, xv.z, xv.w};
    float wr[4] = {wv.x, wv.y, wv.z, wv.w};
#pragma unroll
    for (int j = 0; j < 4; ++j)
#pragma unroll
      for (int c = 0; c < 4; ++c)
        acc[j][c] = fmaf(xr[j], wr[c], acc[j][c]);
  }
  float4 as = *(const float4*)(a1 + c0);
  float4 ad = *(const float4*)(a1 + NHID + c0);
  float asr[4] = {as.x, as.y, as.z, as.w};
  float adr[4] = {ad.x, ad.y, ad.z, ad.w};
  float ps[4], pd[4];
#pragma unroll
  for (int j = 0; j < 4; ++j) {
    int gr = R0 + r0 + j;
    if (gr < N_NODES) {
      uint2 pk;
      pk.x = packbf(acc[j][0], acc[j][1]);
      pk.y = packbf(acc[j][2], acc[j][3]);
      *(uint2*)&h1u[(size_t)gr * 32 + (c0 >> 1)] = pk;
    }
    float s = 0.f, d = 0.f;
#pragma unroll
    for (int c = 0; c < 4; ++c) {
      s = fmaf(acc[j][c], asr[c], s);
      d = fmaf(acc[j][c], adr[c], d);
    }
    ps[j] = s; pd[j] = d;
  }
#pragma unroll
  for (int j = 0; j < 4; ++j)
#pragma unroll
    for (int off = 1; off < 16; off <<= 1) {
      ps[j] += __shfl_xor(ps[j], off);
      pd[j] += __shfl_xor(pd[j], off);
    }
  if (cg == 0) {
#pragma unroll
    for (int j = 0; j < 4; ++j) {
      int gr = R0 + r0 + j;
      if (gr < N_NODES) { s_src[gr] = ps[j]; s_dst[gr] = pd[j]; }
    }
  }
}

// ------ Kernel R: res = x @ res_w^T + res_b (64-row tile, 2x5/thread) ----------
// + fused bucket histogram with per-chunk counts & global reservations
__global__ __launch_bounds__(256) void k_resmm(const float* __restrict__ x,
    const float* __restrict__ res_w, const float* __restrict__ res_b,
    float* __restrict__ res, const int* __restrict__ ei, int* __restrict__ bcnt,
    int* __restrict__ ccnt, int* __restrict__ cbase) {
  __shared__ float xT[NFEAT * 64];      // 32 KB
  __shared__ float rwT[NFEAT * NCLASS]; // 20 KB
  int t = threadIdx.x;
  int R0 = blockIdx.x * 64;
  for (int i = t; i < NCLASS * NFEAT; i += 256) {
    int c = i / NFEAT, k = i % NFEAT;
    rwT[k * NCLASS + c] = res_w[i];
  }
#pragma unroll
  for (int it = 0; it < 8; ++it) {
    int i = t + it * 256;
    int r = i >> 5, kq = i & 31;
    int gr = R0 + r;
    float4 v = make_float4(0.f, 0.f, 0.f, 0.f);
    if (gr < N_NODES) v = *(const float4*)(x + (size_t)gr * NFEAT + kq * 4);
    int rw = r ^ ((kq & 7) << 2);
    xT[(kq * 4 + 0) * 64 + rw] = v.x;
    xT[(kq * 4 + 1) * 64 + rw] = v.y;
    xT[(kq * 4 + 2) * 64 + rw] = v.z;
    xT[(kq * 4 + 3) * 64 + rw] = v.w;
  }
  __syncthreads();
  int cg = t & 7, rg = t >> 3;           // 8 col-groups x 32 row-groups
  int c0 = cg * 5, r0 = rg * 2;
  float acc[2][5] = {};
#pragma unroll 4
  for (int k = 0; k < NFEAT; ++k) {
    float2 xv = *(const float2*)&xT[k * 64 + (r0 ^ swz(k))];
    float xr[2] = {xv.x, xv.y};
    float wr[5];
#pragma unroll
    for (int c = 0; c < 5; ++c) wr[c] = rwT[k * NCLASS + c0 + c];
#pragma unroll
    for (int j = 0; j < 2; ++j)
#pragma unroll
      for (int c = 0; c < 5; ++c)
        acc[j][c] = fmaf(xr[j], wr[c], acc[j][c]);
  }
  float bb[5];
#pragma unroll
  for (int c = 0; c < 5; ++c) bb[c] = res_b[c0 + c];
#pragma unroll
  for (int j = 0; j < 2; ++j) {
    int gr = R0 + r0 + j;
    if (gr < N_NODES) {
#pragma unroll
      for (int c = 0; c < 5; ++c)
        res[(size_t)gr * NCLASS + c0 + c] = acc[j][c] + bb[c];
    }
  }
  // ---- fused bucket histogram: per-chunk counts + global reservation ----------
  if (blockIdx.x < NCHUNK) {
    __syncthreads();
    int* cnt = (int*)xT;
    for (int i = t; i < NBUCK; i += 256) cnt[i] = 0;
    __syncthreads();
    int e0 = blockIdx.x * CHUNK;
    int ecnt = min(CHUNK, N_EDGES - e0);
    for (int i = t; i < ecnt; i += 256)
      atomicAdd(&cnt[ei[e0 + i] >> 6], 1);
    __syncthreads();
    for (int i = t; i < NBUCK; i += 256) {
      int c = cnt[i];
      int base = (c > 0) ? atomicAdd(&bcnt[i], c) : 0;
      ccnt[blockIdx.x * NBUCK + i] = c;
      cbase[blockIdx.x * NBUCK + i] = base;
    }
  }
}

// ------ Kernel C: scan buckets -> gptr -----------------------------------------
__global__ __launch_bounds__(256) void k_bscan(const int* __restrict__ bcnt,
    int* __restrict__ gptr) {
  __shared__ int psum[256];
  int t = threadIdx.x;
  int base = t * 4;
  int s[4];
#pragma unroll
  for (int j = 0; j < 4; ++j)
    s[j] = (base + j < NBUCK) ? bcnt[base + j] : 0;
  int local = s[0] + s[1] + s[2] + s[3];
  psum[t] = local;
  __syncthreads();
#pragma unroll
  for (int o = 1; o < 256; o <<= 1) {
    int v = (t >= o) ? psum[t - o] : 0;
    __syncthreads();
    psum[t] += v;
    __syncthreads();
  }
  int excl = psum[t] - local;
#pragma unroll
  for (int j = 0; j < 4; ++j) {
    if (base + j < NBUCK) gptr[base + j] = excl;
    excl += s[j];
  }
  if (t == 255) gptr[NBUCK] = psum[255];
}

// ------ Kernel D: bucket scatter, single edge pass (bases precomputed) ---------
__global__ __launch_bounds__(256) void k_bscatter(const int* __restrict__ ei,
    const float* __restrict__ adj, const int* __restrict__ gptr,
    const int* __restrict__ ccnt, const int* __restrict__ cbase,
    uint2* __restrict__ edata) {
  __shared__ int cnt[NBUCK];
  __shared__ int off[NBUCK];
  __shared__ int gbase[NBUCK];
  __shared__ int po[NBUCK];
  __shared__ int psum[256];
  __shared__ uint2 stage[CHUNK];   // 32 KB
  int t = threadIdx.x;
  int cix = blockIdx.x;
  int e0 = cix * CHUNK;
  int ecnt = min(CHUNK, N_EDGES - e0);
  for (int i = t; i < NBUCK; i += 256) {
    int c = ccnt[cix * NBUCK + i];
    cnt[i] = c;
    gbase[i] = gptr[i] + cbase[cix * NBUCK + i];
    po[i] = 0;
  }
  __syncthreads();
  int base = t * 4;
  int s0 = (base < NBUCK) ? cnt[base] : 0;
  int s1 = (base + 1 < NBUCK) ? cnt[base + 1] : 0;
  int s2 = (base + 2 < NBUCK) ? cnt[base + 2] : 0;
  int s3 = (base + 3 < NBUCK) ? cnt[base + 3] : 0;
  int local = s0 + s1 + s2 + s3;
  psum[t] = local;
  __syncthreads();
#pragma unroll
  for (int o = 1; o < 256; o <<= 1) {
    int v = (t >= o) ? psum[t - o] : 0;
    __syncthreads();
    psum[t] += v;
    __syncthreads();
  }
  int excl = psum[t] - local;
  if (base < NBUCK)     off[base]     = excl;
  if (base + 1 < NBUCK) off[base + 1] = excl + s0;
  if (base + 2 < NBUCK) off[base + 2] = excl + s0 + s1;
  if (base + 3 < NBUCK) off[base + 3] = excl + s0 + s1 + s2;
  __syncthreads();
  for (int i = t; i < ecnt; i += 256) {
    int e = e0 + i;
    int row = ei[e], col = ei[N_EDGES + e];
    int b = row >> 6;
    int pos = off[b] + atomicAdd(&po[b], 1);
    stage[pos] = make_uint2(((unsigned)b << 22) | ((unsigned)(row & 63) << 16) |
                            (unsigned)col, __float_as_uint(adj[e]));
  }
  __syncthreads();
  for (int i = t; i < ecnt; i += 256) {
    uint2 v = stage[i];
    int b = v.x >> 22;
    edata[(size_t)gbase[b] + (i - off[b])] = v;
  }
}

// ------ Kernel S: per-bucket CSR + edge weights (s_src via LDS) ----------------
__global__ __launch_bounds__(256) void k_csr(const uint2* __restrict__ edata,
    const int* __restrict__ gptr, const float* __restrict__ s_src,
    const float* __restrict__ s_dst, int* __restrict__ row_ptr,
    unsigned* __restrict__ ecsr) {
  __shared__ int lcnt[BROWS];
  __shared__ int lexcl[BROWS];
  __shared__ int lfill[BROWS];
  __shared__ float ssrc[BROWS];
  int t = threadIdx.x;
  int b = blockIdx.x;
  int es = gptr[b], ee = gptr[b + 1];
  if (t < BROWS) {
    lcnt[t] = 0; lfill[t] = 0;
    int gn = b * BROWS + t;
    ssrc[t] = (gn < N_NODES) ? s_src[gn] : 0.f;
  }
  __syncthreads();
  for (int i = es + t; i < ee; i += 256)
    atomicAdd(&lcnt[(edata[i].x >> 16) & 63u], 1);
  __syncthreads();
  if (t < 64) {  // wave 0: 64-lane inclusive scan
    int v = lcnt[t];
    int sc = v;
#pragma unroll
    for (int o = 1; o < 64; o <<= 1) {
      int u = __shfl_up(sc, o);
      if (t >= o) sc += u;
    }
    lexcl[t] = sc - v;
    int gn = b * BROWS + t;
    if (gn < N_NODES) row_ptr[gn] = es + sc - v;
  }
  if (b == NBUCK - 1 && t == 0) row_ptr[N_NODES] = ee;
  __syncthreads();
  for (int i = es + t; i < ee; i += 256) {
    uint2 v = edata[i];
    int rl = (v.x >> 16) & 63;
    int col = v.x & 0xffffu;
    float sc = ssrc[rl] + s_dst[col];
    sc = (sc > 0.f) ? sc : 0.2f * sc;                      // leaky_relu(0.2)
    float wv = __uint_as_float(v.y) / (1.f + __expf(-sc)); // sigmoid * adj
    int pos = es + lexcl[rl] + atomicAdd(&lfill[rl], 1);
    ecsr[pos] = bf16hi(wv) | (unsigned)col;
  }
}

// ------ Kernel E: agg1 edge-streaming (32-edge edata prefetch per request) -----
__global__ __launch_bounds__(256) void k_agg1(const unsigned* __restrict__ h1u,
    const unsigned* __restrict__ edata, const int* __restrict__ row_ptr,
    unsigned* __restrict__ h1o) {
  __shared__ int rps[NPB + 1];
  __shared__ float accs[NPB][NHID];   // 4 KB
  int t = threadIdx.x;
  int n0 = blockIdx.x * NPB;
  if (t <= NPB) rps[t] = row_ptr[min(n0 + t, N_NODES)];
  for (int i = t; i < NPB * NHID / 4; i += 256)
    ((float4*)&accs[0][0])[i] = make_float4(0.f, 0.f, 0.f, 0.f);
  __syncthreads();
  int e0 = rps[0], e1 = rps[NPB];
  int span = e1 - e0;
  int gid = t >> 5, s = t & 31;
  int chunk = (span + 7) >> 3;
  int es = e0 + gid * chunk;
  int ee = min(es + chunk, e1);
  if (es < ee) {
    int lo = 0, hi = NPB - 1;
    while (lo < hi) { int mid = (lo + hi) >> 1; if (rps[mid + 1] <= es) lo = mid + 1; else hi = mid; }
    int r = lo, nxt = rps[r + 1];
    float acc0 = 0.f, acc1 = 0.f;
    int e = es;
    while (e < ee) {
      int mm = ee - e; if (mm > 32) mm = 32;
      unsigned ue = (s < mm) ? edata[e + s] : 0u;   // one request per 32 edges
#pragma unroll
      for (int sub = 0; sub < 4; ++sub) {
        int b0 = sub * 8;
        if (b0 < mm) {
          int m = mm - b0; if (m > 8) m = 8;
          unsigned u[8], v[8];
#pragma unroll
          for (int i = 0; i < 8; ++i) u[i] = __shfl(ue, b0 + i, 32);
#pragma unroll
          for (int i = 0; i < 8; ++i) if (i < m) v[i] = h1u[(size_t)(u[i] & 0xffffu) * 32 + s];
#pragma unroll
          for (int i = 0; i < 8; ++i) if (i < m) {
            while (e + b0 + i >= nxt) {
              atomicAdd(&accs[r][2 * s], acc0);
              atomicAdd(&accs[r][2 * s + 1], acc1);
              acc0 = acc1 = 0.f; ++r; nxt = rps[r + 1];
            }
            float wv = hi16(u[i]);
            acc0 = fmaf(wv, lo16(v[i]), acc0);
            acc1 = fmaf(wv, hi16(v[i]), acc1);
          }
        }
      }
      e += mm;
    }
    atomicAdd(&accs[r][2 * s], acc0);
    atomicAdd(&accs[r][2 * s + 1], acc1);
  }
  __syncthreads();
  for (int i = t; i < NPB * 32; i += 256) {
    int n = i >> 5, c = i & 31;
    int gn = n0 + n;
    if (gn < N_NODES)
      h1o[(size_t)gn * 32 + c] =
          packbf(fmaxf(accs[n][2 * c], 0.f), fmaxf(accs[n][2 * c + 1], 0.f));
  }
}

// ------ Kernel G: h2 = h1o @ W2 (bf16 in, bf16 out, stride 48 ushorts) ---------
__global__ __launch_bounds__(256) void k_h2mm(const unsigned* __restrict__ h1o,
    const float* __restrict__ W2, unsigned short* __restrict__ h2s) {
  __shared__ unsigned xs[H2ROWS * 32];  // swizzled, 8 KB
  __shared__ float W2s[NHID * NCLASS];  // 10 KB
  int t = threadIdx.x;
  int R0 = blockIdx.x * H2ROWS;
  for (int i = t; i < NHID * NCLASS; i += 256) W2s[i] = W2[i];
  for (int i = t; i < H2ROWS * 32; i += 256) {
    int r = i >> 5, ku = i & 31;
    int gr = R0 + r;
    unsigned v = (gr < N_NODES) ? h1o[(size_t)gr * 32 + ku] : 0u;
    xs[r * 32 + (ku ^ (r & 31))] = v;
  }
  __syncthreads();
  int q = t & 31, cg = t >> 5;
  int c0 = cg * 5;
  float acc[2][5] = {};
#pragma unroll 8
  for (int ku = 0; ku < 32; ++ku) {
    unsigned ua = xs[q * 32 + (ku ^ q)];
    unsigned ub = xs[(q + 32) * 32 + (ku ^ q)];
    float a0 = lo16(ua), a1 = hi16(ua);
    float b0 = lo16(ub), b1 = hi16(ub);
#pragma unroll
    for (int c = 0; c < 5; ++c) {
      float w0 = W2s[(2 * ku) * NCLASS + c0 + c];
      float w1 = W2s[(2 * ku + 1) * NCLASS + c0 + c];
      acc[0][c] = fmaf(a0, w0, acc[0][c]);
      acc[0][c] = fmaf(a1, w1, acc[0][c]);
      acc[1][c] = fmaf(b0, w0, acc[1][c]);
      acc[1][c] = fmaf(b1, w1, acc[1][c]);
    }
  }
#pragma unroll
  for (int j = 0; j < 2; ++j) {
    int gr = R0 + q + j * 32;
    if (gr < N_NODES) {
#pragma unroll
      for (int c = 0; c < 5; ++c)
        h2s[(size_t)gr * H2STRIDE + c0 + c] = (unsigned short)(bf16hi(acc[j][c]) >> 16);
    }
  }
}

// ------ Kernel F: agg2 edge-streaming (32-edge prefetch) + res + LN ------------
__global__ __launch_bounds__(256) void k_agg2(const unsigned short* __restrict__ h2s,
    const unsigned* __restrict__ edata, const int* __restrict__ row_ptr,
    const float* __restrict__ res, const float* __restrict__ ln_g,
    const float* __restrict__ ln_b, float* __restrict__ out) {
  __shared__ int rps[NPB + 1];
  __shared__ float accs[NPB][NCLASS];   // 2.5 KB
  int t = threadIdx.x;
  int n0 = blockIdx.x * NPB;
  if (t <= NPB) rps[t] = row_ptr[min(n0 + t, N_NODES)];
  for (int i = t; i < NPB * NCLASS; i += 256) ((float*)accs)[i] = 0.f;
  __syncthreads();
  int e0 = rps[0], e1 = rps[NPB];
  int span = e1 - e0;
  int gid = t >> 5, s = t & 31;
  int chunk = (span + 7) >> 3;
  int es = e0 + gid * chunk;
  int ee = min(es + chunk, e1);
  bool act = (s < 20);
  if (es < ee) {
    int lo = 0, hi = NPB - 1;
    while (lo < hi) { int mid = (lo + hi) >> 1; if (rps[mid + 1] <= es) lo = mid + 1; else hi = mid; }
    int r = lo, nxt = rps[r + 1];
    float acc0 = 0.f, acc1 = 0.f;
    int e = es;
    while (e < ee) {
      int mm = ee - e; if (mm > 32) mm = 32;
      unsigned ue = (s < mm) ? edata[e + s] : 0u;   // one request per 32 edges
#pragma unroll
      for (int sub = 0; sub < 4; ++sub) {
        int b0 = sub * 8;
        if (b0 < mm) {
          int m = mm - b0; if (m > 8) m = 8;
          unsigned u[8], v[8];
#pragma unroll
          for (int i = 0; i < 8; ++i) u[i] = __shfl(ue, b0 + i, 32);
#pragma unroll
          for (int i = 0; i < 8; ++i) {
            v[i] = 0u;
            if (i < m && act)
              v[i] = *(const unsigned*)(h2s + (size_t)(u[i] & 0xffffu) * H2STRIDE + 2 * s);
          }
#pragma unroll
          for (int i = 0; i < 8; ++i) if (i < m) {
            while (e + b0 + i >= nxt) {
              if (act) {
                atomicAdd(&accs[r][2 * s], acc0);
                atomicAdd(&accs[r][2 * s + 1], acc1);
              }
              acc0 = acc1 = 0.f; ++r; nxt = rps[r + 1];
            }
            float wv = hi16(u[i]);
            acc0 = fmaf(wv, lo16(v[i]), acc0);
            acc1 = fmaf(wv, hi16(v[i]), acc1);
          }
        }
      }
      e += mm;
    }
    if (act) {
      atomicAdd(&accs[r][2 * s], acc0);
      atomicAdd(&accs[r][2 * s + 1], acc1);
    }
  }
  __syncthreads();
  int wave = t >> 6, lane = t & 63;
  for (int k = 0; k < NPB / 4; ++k) {
    int n = wave * (NPB / 4) + k;
    int gn = n0 + n;
    if (gn >= N_NODES) break;
    float y = 0.f;
    if (lane < NCLASS)
      y = fmaxf(accs[n][lane], 0.f) + res[(size_t)gn * NCLASS + lane];
    float s1 = y, s2 = y * y;
#pragma unroll
    for (int off = 1; off < 64; off <<= 1) {
      s1 += __shfl_xor(s1, off);
      s2 += __shfl_xor(s2, off);
    }
    float mu = s1 / (float)NCLASS;
    float var = s2 / (float)NCLASS - mu * mu;
    float inv = rsqrtf(var + LN_EPS);
    if (lane < NCLASS)
      out[(size_t)gn * NCLASS + lane] = (y - mu) * inv * ln_g[lane] + ln_b[lane];
  }
}

// -------------------------------------------------------------------------------
extern "C" void kernel_launch(void* const* d_in, const int* in_sizes, int n_in,
                              void* d_out, int out_size, void* d_ws, size_t ws_size,
                              hipStream_t stream) {
  const float* x     = (const float*)d_in[0];
  const int*   ei    = (const int*)  d_in[1];
  const float* adj   = (const float*)d_in[2];
  const float* W1    = (const float*)d_in[3];
  const float* a1    = (const float*)d_in[4];
  const float* W2    = (const float*)d_in[5];
  const float* res_w = (const float*)d_in[6];
  const float* res_b = (const float*)d_in[7];
  const float* ln_g  = (const float*)d_in[8];
  const float* ln_b  = (const float*)d_in[9];
  float* out = (float*)d_out;

  char* ws = (char*)d_ws;
  size_t off = 0;
  auto alloc = [&](size_t bytes) -> void* {
    void* p = (void*)(ws + off);
    off += (bytes + 255) & ~(size_t)255;
    return p;
  };

  unsigned*       h1u     = (unsigned*)alloc((size_t)N_NODES * 32 * 4);  // bf16x2
  float*          s_src   = (float*)alloc((size_t)N_NODES * 4);
  float*          s_dst   = (float*)alloc((size_t)N_NODES * 4);
  int*            bcnt    = (int*)alloc((size_t)NBUCK * 4);
  int*            gptr    = (int*)alloc((size_t)(NBUCK + 1) * 4);
  int*            ccnt    = (int*)alloc((size_t)NCHUNK * NBUCK * 4);
  int*            cbase   = (int*)alloc((size_t)NCHUNK * NBUCK * 4);
  int*            row_ptr = (int*)alloc((size_t)(N_NODES + 1) * 4);
  uint2*          edata   = (uint2*)alloc((size_t)N_EDGES * 8);
  unsigned*       ecsr    = (unsigned*)alloc((size_t)N_EDGES * 4);
  unsigned*       h1o     = (unsigned*)alloc((size_t)N_NODES * 32 * 4);  // bf16x2
  unsigned short* h2s     = (unsigned short*)alloc((size_t)N_NODES * H2STRIDE * 2);
  float*          res     = (float*)alloc((size_t)N_NODES * NCLASS * 4);
  (void)ws_size; (void)in_sizes; (void)n_in; (void)out_size;

  const int NBLK_H1  = (N_NODES + 63) / 64;              // 782
  const int NBLK_RES = (N_NODES + 63) / 64;              // 782
  const int NBLK_H2  = (N_NODES + H2ROWS - 1) / H2ROWS;  // 782
  const int NBLK_AGG = (N_NODES + NPB - 1) / NPB;        // 3125

  k_h1mm<<<NBLK_H1, 256, 0, stream>>>(x, W1, a1, h1u, s_src, s_dst, bcnt);
  k_resmm<<<NBLK_RES, 256, 0, stream>>>(x, res_w, res_b, res, ei, bcnt, ccnt, cbase);
  k_bscan<<<1, 256, 0, stream>>>(bcnt, gptr);
  k_bscatter<<<NCHUNK, 256, 0, stream>>>(ei, adj, gptr, ccnt, cbase, edata);
  k_csr<<<NBUCK, 256, 0, stream>>>(edata, gptr, s_src, s_dst, row_ptr, ecsr);
  k_agg1<<<NBLK_AGG, 256, 0, stream>>>(h1u, ecsr, row_ptr, h1o);
  k_h2mm<<<NBLK_H2, 256, 0, stream>>>(h1o, W2, h2s);
  k_agg2<<<NBLK_AGG, 256, 0, stream>>>(h2s, ecsr, row_ptr, res, ln_g, ln_b, out);
}